// Round 2
// baseline (2272.721 us; speedup 1.0000x reference)
//
#include <hip/hip_runtime.h>

#define N_NODES 100000
#define N_EDGES 1600000
#define DIM 128
#define NPB 8            // nodes per block in the 128x128 MLP kernel
#define NPBF 16          // nodes per block in the final-layer kernel
#define ODIM 16          // final layer output dim (num classes)
#define LDU 132          // padded LDS leading dim for final kernel

// ---------------------------------------------------------------------------
// Edge scatter: agg[dst] += x[src] * (use_w ? ew[e] : 1)
// One 64-lane group per edge; lane handles features {lane, lane+64}.
// NOTE: harness delivers edge_index as int32 (int64 in reference is converted).
// ---------------------------------------------------------------------------
__global__ __launch_bounds__(256) void scatter_kernel(
    const float* __restrict__ x,
    const int* __restrict__ src,
    const int* __restrict__ dst,
    const float* __restrict__ ew,
    float* __restrict__ agg,
    int use_w) {
  int lane = threadIdx.x & 63;
  int gpb = blockDim.x >> 6;                       // groups per block (4)
  int group = blockIdx.x * gpb + (threadIdx.x >> 6);
  int stride = gridDim.x * gpb;
  for (int e = group; e < N_EDGES; e += stride) {
    int s = src[e];
    int d = dst[e];
    const float* xr = x + (size_t)s * DIM;
    float v0 = xr[lane];
    float v1 = xr[lane + 64];
    if (use_w) {
      float w = ew[e];
      v0 *= w;
      v1 *= w;
    }
    float* ar = agg + (size_t)d * DIM;
    unsafeAtomicAdd(ar + lane, v0);
    unsafeAtomicAdd(ar + lane + 64, v1);
  }
}

// ---------------------------------------------------------------------------
// Fused GIN MLP (128 -> 128): u = (1+eps)*x + agg; v = relu(u @ W + b);
// out = v / max(||v||, 1e-12). Block = 128 threads (thread t = out feature t),
// NPB nodes per block; u staged in LDS, read back as broadcast float4.
// `out` MAY ALIAS `agg` (block reads only its own rows before the barrier,
// writes only its own rows after) — so no __restrict__ on agg/out.
// ---------------------------------------------------------------------------
__global__ __launch_bounds__(128) void gin_mlp128(
    const float* __restrict__ xin, const float* agg,
    const float* __restrict__ W, const float* __restrict__ b,
    const float* __restrict__ eps_p, float* out) {
  __shared__ __align__(16) float u[NPB][DIM];
  __shared__ float partials[2][NPB];
  int t = threadIdx.x;
  int node0 = blockIdx.x * NPB;
  float epf = 1.0f + *eps_p;
#pragma unroll
  for (int n = 0; n < NPB; n++) {
    size_t idx = (size_t)(node0 + n) * DIM + t;
    u[n][t] = epf * xin[idx] + agg[idx];
  }
  __syncthreads();

  float acc[NPB];
#pragma unroll
  for (int n = 0; n < NPB; n++) acc[n] = 0.0f;

  for (int k = 0; k < DIM; k += 4) {
    float w0 = W[(k + 0) * DIM + t];
    float w1 = W[(k + 1) * DIM + t];
    float w2 = W[(k + 2) * DIM + t];
    float w3 = W[(k + 3) * DIM + t];
#pragma unroll
    for (int n = 0; n < NPB; n++) {
      float4 uv = *(const float4*)&u[n][k];   // broadcast ds_read_b128
      acc[n] = fmaf(uv.x, w0, acc[n]);
      acc[n] = fmaf(uv.y, w1, acc[n]);
      acc[n] = fmaf(uv.z, w2, acc[n]);
      acc[n] = fmaf(uv.w, w3, acc[n]);
    }
  }

  float bj = b[t];
  int lane = t & 63, wave = t >> 6;
  float v[NPB];
#pragma unroll
  for (int n = 0; n < NPB; n++) {
    float vv = fmaxf(acc[n] + bj, 0.0f);
    v[n] = vv;
    float s = vv * vv;
#pragma unroll
    for (int off = 32; off >= 1; off >>= 1) s += __shfl_down(s, off, 64);
    if (lane == 0) partials[wave][n] = s;
  }
  __syncthreads();
#pragma unroll
  for (int n = 0; n < NPB; n++) {
    float norm = sqrtf(partials[0][n] + partials[1][n]);
    float inv = 1.0f / fmaxf(norm, 1e-12f);
    out[(size_t)(node0 + n) * DIM + t] = v[n] * inv;  // trailing relu no-op (v>=0)
  }
}

// ---------------------------------------------------------------------------
// Final layer (128 -> 16): u = (1+eps)*h + agg; logits = relu(u @ W2 + b2);
// probs = softmax(logits). Block = 256 = 16 nodes x 16 features.
// ---------------------------------------------------------------------------
__global__ __launch_bounds__(256) void gin_final(
    const float* __restrict__ xin, const float* __restrict__ agg,
    const float* __restrict__ W, const float* __restrict__ b,
    const float* __restrict__ eps_p, float* __restrict__ out_logits,
    float* __restrict__ out_probs) {
  __shared__ float u[NPBF * LDU];
  int tid = threadIdx.x;
  int node0 = blockIdx.x * NPBF;
  float epf = 1.0f + *eps_p;
  for (int i = tid; i < NPBF * DIM; i += 256) {
    int n = i >> 7, f = i & 127;
    size_t idx = (size_t)(node0 + n) * DIM + f;
    u[n * LDU + f] = epf * xin[idx] + agg[idx];
  }
  __syncthreads();

  int j = tid & 15, ng = tid >> 4;
  float acc = 0.0f;
  for (int k = 0; k < DIM; k++) {
    acc = fmaf(u[ng * LDU + k], W[k * ODIM + j], acc);
  }
  float logit = fmaxf(acc + b[j], 0.0f);

  float mx = logit;
#pragma unroll
  for (int m = 8; m >= 1; m >>= 1) mx = fmaxf(mx, __shfl_xor(mx, m, 16));
  float e = __expf(logit - mx);
  float ssum = e;
#pragma unroll
  for (int m = 8; m >= 1; m >>= 1) ssum += __shfl_xor(ssum, m, 16);
  float prob = e / ssum;

  size_t oidx = (size_t)(node0 + ng) * ODIM + j;
  out_logits[oidx] = logit;
  out_probs[oidx] = prob;
}

// ---------------------------------------------------------------------------
extern "C" void kernel_launch(void* const* d_in, const int* in_sizes, int n_in,
                              void* d_out, int out_size, void* d_ws, size_t ws_size,
                              hipStream_t stream) {
  const float* x = (const float*)d_in[0];
  const int* ei = (const int*)d_in[1];       // int64 in reference -> int32 on device
  const float* ew = (const float*)d_in[2];
  const float* W0 = (const float*)d_in[3];
  const float* b0 = (const float*)d_in[4];
  const float* e0 = (const float*)d_in[5];
  const float* W1 = (const float*)d_in[6];
  const float* b1 = (const float*)d_in[7];
  const float* e1 = (const float*)d_in[8];
  const float* W2 = (const float*)d_in[9];
  const float* b2 = (const float*)d_in[10];
  const float* e2 = (const float*)d_in[11];
  float* out = (float*)d_out;

  const size_t bufBytes = (size_t)N_NODES * DIM * sizeof(float);  // 51.2 MB
  float* A = (float*)d_ws;                          // region A
  float* B = (float*)((char*)d_ws + bufBytes);      // region B  (total 102.4 MB)
  const int* srcp = ei;
  const int* dstp = ei + N_EDGES;

  dim3 sblk(256), sgrid(8192);
  dim3 gblk(128), ggrid(N_NODES / NPB);    // 12500
  dim3 fblk(256), fgrid(N_NODES / NPBF);   // 6250

  // layer 0: agg0 -> A; h0 = mlp(x, A) -> B
  hipMemsetAsync(A, 0, bufBytes, stream);
  scatter_kernel<<<sgrid, sblk, 0, stream>>>(x, srcp, dstp, ew, A, 1);
  gin_mlp128<<<ggrid, gblk, 0, stream>>>(x, A, W0, b0, e0, B);

  // layer 1: agg1 -> A; h1 = mlp(B, A) -> A (safe alias)
  hipMemsetAsync(A, 0, bufBytes, stream);
  scatter_kernel<<<sgrid, sblk, 0, stream>>>(B, srcp, dstp, ew, A, 1);
  gin_mlp128<<<ggrid, gblk, 0, stream>>>(B, A, W1, b1, e1, A);

  // layer 2: agg2 -> B (no edge weight); final(A, B) -> d_out
  hipMemsetAsync(B, 0, bufBytes, stream);
  scatter_kernel<<<sgrid, sblk, 0, stream>>>(A, srcp, dstp, ew, B, 0);
  gin_final<<<fgrid, fblk, 0, stream>>>(A, B, W2, b2, e2,
                                        out, out + (size_t)N_NODES * ODIM);
}

// Round 3
// 859.003 us; speedup vs baseline: 2.6458x; 2.6458x over previous
//
#include <hip/hip_runtime.h>
#include <hip/hip_bf16.h>

#define N_NODES 100000
#define N_EDGES 1600000
#define DIM 128
#define NPB 8            // nodes per block in the 128x128 MLP kernel
#define ODIM 16          // final layer output dim (num classes)
#define SCAN_CHUNK 1024
#define SCAN_BLOCKS 98   // 98*1024 = 100352 >= N_NODES

// ===========================================================================
// CSR build: counts -> exclusive scan -> fill (src, weight) bucketed by dst.
// Rebuilt every call (ws is re-poisoned); ~40 us total, amortized over 3 uses.
// ===========================================================================
__global__ __launch_bounds__(256) void hist_kernel(
    const int* __restrict__ dst, int* __restrict__ counts) {
  int e = blockIdx.x * 256 + threadIdx.x;
  if (e < N_EDGES) atomicAdd(&counts[dst[e]], 1);
}

__global__ __launch_bounds__(256) void scan1_kernel(
    const int* __restrict__ counts, int* __restrict__ local_excl,
    int* __restrict__ blockSums) {
  __shared__ int ts[256];
  int t = threadIdx.x;
  int base = blockIdx.x * SCAN_CHUNK + t * 4;
  int v[4];
#pragma unroll
  for (int j = 0; j < 4; j++) v[j] = (base + j < N_NODES) ? counts[base + j] : 0;
  int s = v[0] + v[1] + v[2] + v[3];
  ts[t] = s;
  __syncthreads();
  for (int off = 1; off < 256; off <<= 1) {
    int a = (t >= off) ? ts[t - off] : 0;
    __syncthreads();
    ts[t] += a;
    __syncthreads();
  }
  if (t == 255) blockSums[blockIdx.x] = ts[255];
  int run = ts[t] - s;   // exclusive prefix for this thread
#pragma unroll
  for (int j = 0; j < 4; j++) {
    if (base + j < N_NODES) local_excl[base + j] = run;
    run += v[j];
  }
}

__global__ __launch_bounds__(128) void scan2_kernel(int* __restrict__ blockSums) {
  __shared__ int bs[128];
  int t = threadIdx.x;
  int orig = (t < SCAN_BLOCKS) ? blockSums[t] : 0;
  bs[t] = orig;
  __syncthreads();
  for (int off = 1; off < 128; off <<= 1) {
    int a = (t >= off) ? bs[t - off] : 0;
    __syncthreads();
    bs[t] += a;
    __syncthreads();
  }
  if (t < SCAN_BLOCKS) blockSums[t] = bs[t] - orig;  // exclusive
}

__global__ __launch_bounds__(256) void scan3_kernel(
    int* __restrict__ row_ptr, const int* __restrict__ blockSums,
    int* __restrict__ cursor) {
  int t = threadIdx.x;
  int base = blockIdx.x * SCAN_CHUNK + t * 4;
  int off = blockSums[blockIdx.x];
#pragma unroll
  for (int j = 0; j < 4; j++) {
    if (base + j < N_NODES) {
      int v = row_ptr[base + j] + off;
      row_ptr[base + j] = v;
      cursor[base + j] = v;
    }
  }
  if (blockIdx.x == 0 && t == 0) row_ptr[N_NODES] = N_EDGES;
}

__global__ __launch_bounds__(256) void fill_kernel(
    const int* __restrict__ src, const int* __restrict__ dst,
    const float* __restrict__ ew, int* __restrict__ cursor,
    int* __restrict__ esrc, float* __restrict__ ewf) {
  int e = blockIdx.x * 256 + threadIdx.x;
  if (e >= N_EDGES) return;
  int d = dst[e];
  int pos = atomicAdd(&cursor[d], 1);
  esrc[pos] = src[e];
  ewf[pos] = ew[e];
}

// ===========================================================================
// Gather aggregation (replaces atomic scatter): one 64-lane wave per node,
// lane holds features {2*lane, 2*lane+1}; row read = one dwordx2 per lane
// (512B coalesced). Writes each agg row exactly once -> no atomics, no memset.
// ===========================================================================
__global__ __launch_bounds__(256) void gather_f32(
    const float* __restrict__ x, const int* __restrict__ row_ptr,
    const int* __restrict__ esrc, const float* __restrict__ ewf,
    float* __restrict__ agg) {
  int lane = threadIdx.x & 63;
  int node = blockIdx.x * 4 + (threadIdx.x >> 6);
  if (node >= N_NODES) return;
  int a = row_ptr[node], bnd = row_ptr[node + 1];
  float acc0 = 0.0f, acc1 = 0.0f;
  for (int j = a; j < bnd; j++) {
    int s = esrc[j];
    float w = ewf[j];
    const float2 v = *(const float2*)(x + (size_t)s * DIM + 2 * lane);
    acc0 = fmaf(w, v.x, acc0);
    acc1 = fmaf(w, v.y, acc1);
  }
  float2 st = {acc0, acc1};
  *(float2*)(agg + (size_t)node * DIM + 2 * lane) = st;
}

__global__ __launch_bounds__(256) void gather_bf16(
    const __hip_bfloat16* __restrict__ h, const int* __restrict__ row_ptr,
    const int* __restrict__ esrc, const float* __restrict__ ewf,
    float* __restrict__ agg) {
  int lane = threadIdx.x & 63;
  int node = blockIdx.x * 4 + (threadIdx.x >> 6);
  if (node >= N_NODES) return;
  int a = row_ptr[node], bnd = row_ptr[node + 1];
  float acc0 = 0.0f, acc1 = 0.0f;
  const unsigned int* hu = (const unsigned int*)h;
  for (int j = a; j < bnd; j++) {
    int s = esrc[j];
    float w = ewf[j];
    unsigned int pv = hu[(size_t)s * (DIM / 2) + lane];
    float f0 = __uint_as_float(pv << 16);          // feature 2*lane
    float f1 = __uint_as_float(pv & 0xFFFF0000u);  // feature 2*lane+1
    acc0 = fmaf(w, f0, acc0);
    acc1 = fmaf(w, f1, acc1);
  }
  float2 st = {acc0, acc1};
  *(float2*)(agg + (size_t)node * DIM + 2 * lane) = st;
}

// ===========================================================================
// Fused GIN MLP (128->128): u = (1+eps)*x + agg; v = relu(u@W + b);
// out = v / max(||v||,1e-12), stored bf16. Tin selects f32/bf16 input.
// In-place use (out row == xin row) is safe: block touches only its 8 rows.
// ===========================================================================
template <int IN_BF16>
__global__ __launch_bounds__(128) void gin_mlp128(
    const void* __restrict__ xin_v, const float* __restrict__ agg,
    const float* __restrict__ W, const float* __restrict__ b,
    const float* __restrict__ eps_p, __hip_bfloat16* out) {
  __shared__ __align__(16) float u[NPB][DIM];
  __shared__ float partials[2][NPB];
  int t = threadIdx.x;
  int node0 = blockIdx.x * NPB;
  float epf = 1.0f + *eps_p;
#pragma unroll
  for (int n = 0; n < NPB; n++) {
    size_t idx = (size_t)(node0 + n) * DIM + t;
    float xv;
    if (IN_BF16) xv = __bfloat162float(((const __hip_bfloat16*)xin_v)[idx]);
    else xv = ((const float*)xin_v)[idx];
    u[n][t] = epf * xv + agg[idx];
  }
  __syncthreads();

  float acc[NPB];
#pragma unroll
  for (int n = 0; n < NPB; n++) acc[n] = 0.0f;

  for (int k = 0; k < DIM; k += 4) {
    float w0 = W[(k + 0) * DIM + t];
    float w1 = W[(k + 1) * DIM + t];
    float w2 = W[(k + 2) * DIM + t];
    float w3 = W[(k + 3) * DIM + t];
#pragma unroll
    for (int n = 0; n < NPB; n++) {
      float4 uv = *(const float4*)&u[n][k];   // broadcast ds_read_b128
      acc[n] = fmaf(uv.x, w0, acc[n]);
      acc[n] = fmaf(uv.y, w1, acc[n]);
      acc[n] = fmaf(uv.z, w2, acc[n]);
      acc[n] = fmaf(uv.w, w3, acc[n]);
    }
  }

  float bj = b[t];
  int lane = t & 63, wave = t >> 6;
  float v[NPB];
#pragma unroll
  for (int n = 0; n < NPB; n++) {
    float vv = fmaxf(acc[n] + bj, 0.0f);
    v[n] = vv;
    float s = vv * vv;
#pragma unroll
    for (int off = 32; off >= 1; off >>= 1) s += __shfl_down(s, off, 64);
    if (lane == 0) partials[wave][n] = s;
  }
  __syncthreads();
#pragma unroll
  for (int n = 0; n < NPB; n++) {
    float norm = sqrtf(partials[0][n] + partials[1][n]);
    float inv = 1.0f / fmaxf(norm, 1e-12f);
    out[(size_t)(node0 + n) * DIM + t] = __float2bfloat16(v[n] * inv);
  }
}

// ===========================================================================
// Layer 2, projection-first (aggregation is linear): y = h1 @ W2 (128->16).
// Block 256 = 16 nodes x 16 out-features; h1 rows staged in LDS (pad 132).
// ===========================================================================
#define LDU 132
__global__ __launch_bounds__(256) void proj16_kernel(
    const __hip_bfloat16* __restrict__ h, const float* __restrict__ W,
    float* __restrict__ y) {
  __shared__ float u[16 * LDU];
  int tid = threadIdx.x;
  int node0 = blockIdx.x * 16;
  const unsigned int* hu = (const unsigned int*)(h + (size_t)node0 * DIM);
  for (int i = tid; i < 16 * (DIM / 2); i += 256) {
    unsigned int pv = hu[i];
    int e = 2 * i, n = e >> 7, f = e & 127;
    u[n * LDU + f] = __uint_as_float(pv << 16);
    u[n * LDU + f + 1] = __uint_as_float(pv & 0xFFFF0000u);
  }
  __syncthreads();
  int j = tid & 15, ng = tid >> 4;
  float acc = 0.0f;
  for (int k = 0; k < DIM; k++) acc = fmaf(u[ng * LDU + k], W[k * ODIM + j], acc);
  y[(size_t)(node0 + ng) * ODIM + j] = acc;
}

// Aggregate 16-dim y rows via CSR (no weights). Wave = 4 edge-quarters x 16 f.
__global__ __launch_bounds__(256) void gather16_kernel(
    const float* __restrict__ y, const int* __restrict__ row_ptr,
    const int* __restrict__ esrc, float* __restrict__ aggy) {
  int lane = threadIdx.x & 63;
  int node = blockIdx.x * 4 + (threadIdx.x >> 6);
  if (node >= N_NODES) return;
  int f = lane & 15, eq = lane >> 4;
  int a = row_ptr[node], bnd = row_ptr[node + 1];
  float acc = 0.0f;
  for (int j = a + eq; j < bnd; j += 4) {
    int s = esrc[j];
    acc += y[(size_t)s * ODIM + f];
  }
  acc += __shfl_xor(acc, 16, 64);
  acc += __shfl_xor(acc, 32, 64);
  if (eq == 0) aggy[(size_t)node * ODIM + f] = acc;
}

// logits = relu((1+eps)*y + aggy + b); probs = softmax(logits).
__global__ __launch_bounds__(256) void final16_kernel(
    const float* __restrict__ y, const float* __restrict__ aggy,
    const float* __restrict__ b, const float* __restrict__ eps_p,
    float* __restrict__ out_logits, float* __restrict__ out_probs) {
  int tid = threadIdx.x;
  int j = tid & 15, ng = tid >> 4;
  int node = blockIdx.x * 16 + ng;
  float epf = 1.0f + *eps_p;
  size_t idx = (size_t)node * ODIM + j;
  float logit = fmaxf(fmaf(epf, y[idx], aggy[idx]) + b[j], 0.0f);

  float mx = logit;
#pragma unroll
  for (int m = 8; m >= 1; m >>= 1) mx = fmaxf(mx, __shfl_xor(mx, m, 16));
  float e = __expf(logit - mx);
  float ssum = e;
#pragma unroll
  for (int m = 8; m >= 1; m >>= 1) ssum += __shfl_xor(ssum, m, 16);
  out_logits[idx] = logit;
  out_probs[idx] = e / ssum;
}

// ===========================================================================
extern "C" void kernel_launch(void* const* d_in, const int* in_sizes, int n_in,
                              void* d_out, int out_size, void* d_ws, size_t ws_size,
                              hipStream_t stream) {
  const float* x = (const float*)d_in[0];
  const int* ei = (const int*)d_in[1];       // int64 in reference -> int32 on device
  const float* ew = (const float*)d_in[2];
  const float* W0 = (const float*)d_in[3];
  const float* b0 = (const float*)d_in[4];
  const float* e0 = (const float*)d_in[5];
  const float* W1 = (const float*)d_in[6];
  const float* b1 = (const float*)d_in[7];
  const float* e1 = (const float*)d_in[8];
  const float* W2 = (const float*)d_in[9];
  const float* b2 = (const float*)d_in[10];
  const float* e2 = (const float*)d_in[11];
  float* out = (float*)d_out;

  const int* srcp = ei;
  const int* dstp = ei + N_EDGES;

  // ---- workspace layout (total ~90.6 MB; 102.4 MB proven available) ----
  char* ws = (char*)d_ws;
  float* A = (float*)ws;                                   // 51.2 MB (f32 agg)
  __hip_bfloat16* H = (__hip_bfloat16*)(ws + 51200000 + 1600000);  // 25.6 MB
  // note: offsets kept 16B-aligned, simple fixed layout:
  size_t off = 0;
  A = (float*)(ws + off);            off += (size_t)N_NODES * DIM * 4;   // 51.2 MB
  H = (__hip_bfloat16*)(ws + off);   off += (size_t)N_NODES * DIM * 2;   // 25.6 MB
  int* esrc = (int*)(ws + off);      off += (size_t)N_EDGES * 4;         // 6.4 MB
  float* ewf = (float*)(ws + off);   off += (size_t)N_EDGES * 4;         // 6.4 MB
  int* row_ptr = (int*)(ws + off);   off += (size_t)(N_NODES + 16) * 4;
  int* cursor = (int*)(ws + off);    off += (size_t)(N_NODES + 16) * 4;  // also counts
  int* blockSums = (int*)(ws + off); off += 1024;

  float* yA = A;                       // 6.4 MB, reuses A after layer-1 MLP
  float* aggyA = A + (size_t)2 * N_NODES * ODIM;  // disjoint from yA

  // ---- build CSR (dst-bucketed) ----
  hipMemsetAsync(cursor, 0, N_NODES * sizeof(int), stream);  // counts
  hist_kernel<<<N_EDGES / 256, 256, 0, stream>>>(dstp, cursor);
  scan1_kernel<<<SCAN_BLOCKS, 256, 0, stream>>>(cursor, row_ptr, blockSums);
  scan2_kernel<<<1, 128, 0, stream>>>(blockSums);
  scan3_kernel<<<SCAN_BLOCKS, 256, 0, stream>>>(row_ptr, blockSums, cursor);
  fill_kernel<<<N_EDGES / 256, 256, 0, stream>>>(srcp, dstp, ew, cursor, esrc, ewf);

  dim3 gthr(256);
  int ggrid = (N_NODES + 3) / 4;       // 25000
  int mgrid = N_NODES / NPB;           // 12500
  int fgrid = N_NODES / 16;            // 6250

  // layer 0: agg0 -> A; h0 = mlp(x, A) -> H (bf16)
  gather_f32<<<ggrid, gthr, 0, stream>>>(x, row_ptr, esrc, ewf, A);
  gin_mlp128<0><<<mgrid, 128, 0, stream>>>(x, A, W0, b0, e0, H);

  // layer 1: agg1 -> A; h1 = mlp(H, A) -> H (in-place, bf16)
  gather_bf16<<<ggrid, gthr, 0, stream>>>(H, row_ptr, esrc, ewf, A);
  gin_mlp128<1><<<mgrid, 128, 0, stream>>>(H, A, W1, b1, e1, H);

  // layer 2 (projection-first, no edge weight): y = H @ W2; aggy = gather(y)
  proj16_kernel<<<fgrid, 256, 0, stream>>>(H, W2, yA);
  gather16_kernel<<<ggrid, gthr, 0, stream>>>(yA, row_ptr, esrc, aggyA);
  final16_kernel<<<fgrid, 256, 0, stream>>>(yA, aggyA, b2, e2,
                                            out, out + (size_t)N_NODES * ODIM);
}

// Round 4
// 559.905 us; speedup vs baseline: 4.0591x; 1.5342x over previous
//
#include <hip/hip_runtime.h>
#include <hip/hip_bf16.h>

#define N_NODES 100000
#define N_EDGES 1600000
#define DIM 128
#define ODIM 16
#define SCAN_CHUNK 1024
#define SCAN_BLOCKS 98   // 98*1024 >= N_NODES

typedef unsigned int uint32;
typedef float f32x4 __attribute__((ext_vector_type(4)));
typedef short bf16x8 __attribute__((ext_vector_type(8)));

static __device__ __forceinline__ float bflo(uint32 p) { return __uint_as_float(p << 16); }
static __device__ __forceinline__ float bfhi(uint32 p) { return __uint_as_float(p & 0xFFFF0000u); }
static __device__ __forceinline__ unsigned short f2bf(float f) {
  __hip_bfloat16 h = __float2bfloat16(f);
  return *reinterpret_cast<unsigned short*>(&h);
}
static __device__ __forceinline__ uint32 pk2bf(float a, float b) {
  return (uint32)f2bf(a) | ((uint32)f2bf(b) << 16);
}

// ===========================================================================
// CSR build: counts -> exclusive scan -> fill (src, weight) bucketed by dst.
// ===========================================================================
__global__ __launch_bounds__(256) void hist_kernel(
    const int* __restrict__ dst, int* __restrict__ counts) {
  int e = blockIdx.x * 256 + threadIdx.x;
  if (e < N_EDGES) atomicAdd(&counts[dst[e]], 1);
}

__global__ __launch_bounds__(256) void scan1_kernel(
    const int* __restrict__ counts, int* __restrict__ local_excl,
    int* __restrict__ blockSums) {
  __shared__ int ts[256];
  int t = threadIdx.x;
  int base = blockIdx.x * SCAN_CHUNK + t * 4;
  int v[4];
#pragma unroll
  for (int j = 0; j < 4; j++) v[j] = (base + j < N_NODES) ? counts[base + j] : 0;
  int s = v[0] + v[1] + v[2] + v[3];
  ts[t] = s;
  __syncthreads();
  for (int off = 1; off < 256; off <<= 1) {
    int a = (t >= off) ? ts[t - off] : 0;
    __syncthreads();
    ts[t] += a;
    __syncthreads();
  }
  if (t == 255) blockSums[blockIdx.x] = ts[255];
  int run = ts[t] - s;
#pragma unroll
  for (int j = 0; j < 4; j++) {
    if (base + j < N_NODES) local_excl[base + j] = run;
    run += v[j];
  }
}

__global__ __launch_bounds__(128) void scan2_kernel(int* __restrict__ blockSums) {
  __shared__ int bs[128];
  int t = threadIdx.x;
  int orig = (t < SCAN_BLOCKS) ? blockSums[t] : 0;
  bs[t] = orig;
  __syncthreads();
  for (int off = 1; off < 128; off <<= 1) {
    int a = (t >= off) ? bs[t - off] : 0;
    __syncthreads();
    bs[t] += a;
    __syncthreads();
  }
  if (t < SCAN_BLOCKS) blockSums[t] = bs[t] - orig;
}

__global__ __launch_bounds__(256) void scan3_kernel(
    int* __restrict__ row_ptr, const int* __restrict__ blockSums,
    int* __restrict__ cursor) {
  int t = threadIdx.x;
  int base = blockIdx.x * SCAN_CHUNK + t * 4;
  int off = blockSums[blockIdx.x];
#pragma unroll
  for (int j = 0; j < 4; j++) {
    if (base + j < N_NODES) {
      int v = row_ptr[base + j] + off;
      row_ptr[base + j] = v;
      cursor[base + j] = v;
    }
  }
  if (blockIdx.x == 0 && t == 0) row_ptr[N_NODES] = N_EDGES;
}

__global__ __launch_bounds__(256) void fill_kernel(
    const int* __restrict__ src, const int* __restrict__ dst,
    const float* __restrict__ ew, int* __restrict__ cursor,
    int2* __restrict__ epack) {
  int e = blockIdx.x * 256 + threadIdx.x;
  if (e >= N_EDGES) return;
  int d = dst[e];
  int pos = atomicAdd(&cursor[d], 1);
  epack[pos] = make_int2(src[e], __float_as_int(ew[e]));
}

// ===========================================================================
// Cast x (f32, N x 128) -> packed bf16 pairs (N x 64 uints).
// ===========================================================================
__global__ __launch_bounds__(256) void cast_x_kernel(
    const float2* __restrict__ x2, uint32* __restrict__ Xu) {
  int i = blockIdx.x * 256 + threadIdx.x;   // pair index, 6.4M total
  if (i < N_NODES * (DIM / 2)) {
    float2 v = x2[i];
    Xu[i] = pk2bf(v.x, v.y);
  }
}

// ===========================================================================
// Pack W (f32 K x N) into MFMA B-fragment order, bf16.
// frag f = kc*NT + nt; element [f][lane][j] = W[kc*32 + (lane>>4)*8 + j][nt*16 + (lane&15)]
// ===========================================================================
__global__ __launch_bounds__(256) void packW128_kernel(
    const float* __restrict__ W, unsigned short* __restrict__ out) {
  int idx = blockIdx.x * 256 + threadIdx.x;          // 16384
  int j = idx & 7, lane = (idx >> 3) & 63, nt = (idx >> 9) & 7, kc = idx >> 12;
  int k = kc * 32 + (lane >> 4) * 8 + j;
  int n = nt * 16 + (lane & 15);
  out[idx] = f2bf(W[k * DIM + n]);
}

__global__ __launch_bounds__(256) void packW16_kernel(
    const float* __restrict__ W, unsigned short* __restrict__ out) {
  int idx = blockIdx.x * 256 + threadIdx.x;          // 2048
  if (idx >= 2048) return;
  int j = idx & 7, lane = (idx >> 3) & 63, kc = idx >> 9;
  int k = kc * 32 + (lane >> 4) * 8 + j;
  int n = lane & 15;
  out[idx] = f2bf(W[k * ODIM + n]);
}

// ===========================================================================
// Gather aggregation over CSR, bf16 features in / bf16 agg out.
// One 64-lane wave per node; lane holds feature pair (2*lane, 2*lane+1).
// Edge loop unrolled x4 for MLP (4+ outstanding row loads).
// ===========================================================================
__global__ __launch_bounds__(256) void gather_bf16(
    const uint32* __restrict__ hu, const int* __restrict__ row_ptr,
    const int2* __restrict__ ep, uint32* __restrict__ aggu) {
  int lane = threadIdx.x & 63;
  int node = blockIdx.x * 4 + (threadIdx.x >> 6);
  if (node >= N_NODES) return;
  int a = row_ptr[node], bnd = row_ptr[node + 1];
  float acc0 = 0.0f, acc1 = 0.0f;
  int j = a;
  for (; j + 4 <= bnd; j += 4) {
    int2 e0 = ep[j], e1 = ep[j + 1], e2 = ep[j + 2], e3 = ep[j + 3];
    uint32 p0 = hu[(size_t)e0.x * 64 + lane];
    uint32 p1 = hu[(size_t)e1.x * 64 + lane];
    uint32 p2 = hu[(size_t)e2.x * 64 + lane];
    uint32 p3 = hu[(size_t)e3.x * 64 + lane];
    float w0 = __int_as_float(e0.y), w1 = __int_as_float(e1.y);
    float w2 = __int_as_float(e2.y), w3 = __int_as_float(e3.y);
    acc0 = fmaf(w0, bflo(p0), acc0); acc1 = fmaf(w0, bfhi(p0), acc1);
    acc0 = fmaf(w1, bflo(p1), acc0); acc1 = fmaf(w1, bfhi(p1), acc1);
    acc0 = fmaf(w2, bflo(p2), acc0); acc1 = fmaf(w2, bfhi(p2), acc1);
    acc0 = fmaf(w3, bflo(p3), acc0); acc1 = fmaf(w3, bfhi(p3), acc1);
  }
  for (; j < bnd; j++) {
    int2 e0 = ep[j];
    uint32 p0 = hu[(size_t)e0.x * 64 + lane];
    float w0 = __int_as_float(e0.y);
    acc0 = fmaf(w0, bflo(p0), acc0); acc1 = fmaf(w0, bfhi(p0), acc1);
  }
  aggu[(size_t)node * 64 + lane] = pk2bf(acc0, acc1);
}

// ===========================================================================
// Fused GIN MLP via MFMA (bf16): u = (1+eps)*x + agg  (bf16 in LDS);
// C = U @ W (16x16x32 MFMA, 64 nodes x 128 outs per block, K=128);
// epilogue: +bias, relu, L2-normalize per node row, bf16 out via LDS.
// outH may alias Xu (block touches only its own 64 rows).
// LDS: A-tile 64 x 136 bf16 (17408 B) + B frags 32 KB = 50176 B -> 3 blk/CU.
// ===========================================================================
__global__ __launch_bounds__(256) void gin_mlp_mfma(
    const uint32* Xu, const uint32* __restrict__ Au,
    const unsigned char* __restrict__ pW, const float* __restrict__ b,
    const float* __restrict__ eps_p, uint32* outH) {
  __shared__ __align__(16) unsigned char smem[17408 + 32768];
  unsigned char* As = smem;
  unsigned char* Bs = smem + 17408;

  int tid = threadIdx.x;
  int node0 = blockIdx.x * 64;
  float epf = 1.0f + *eps_p;

  // --- stage U (bf16) into A-tile, row stride 272 B ---
  for (int i = tid; i < 64 * 64; i += 256) {
    int n = i >> 6, fp = i & 63;
    int node = node0 + n;
    int cn = node < N_NODES ? node : N_NODES - 1;
    size_t idx = (size_t)cn * 64 + fp;
    uint32 xv = Xu[idx], av = Au[idx];
    float u0 = fmaf(epf, bflo(xv), bflo(av));
    float u1 = fmaf(epf, bfhi(xv), bfhi(av));
    *(uint32*)(As + n * 272 + fp * 4) = pk2bf(u0, u1);
  }
  // --- stage packed W into LDS ---
  {
    const uint4* Wp = (const uint4*)pW;
    uint4* Bl = (uint4*)Bs;
    for (int i = tid; i < 2048; i += 256) Bl[i] = Wp[i];
  }
  __syncthreads();

  int w = tid >> 6, l = tid & 63;
  int m = l & 15, q = l >> 4;

  f32x4 acc[8];
#pragma unroll
  for (int nt = 0; nt < 8; nt++) acc[nt] = (f32x4){0.f, 0.f, 0.f, 0.f};

  const unsigned char* Abase = As + (w * 16 + m) * 272 + q * 16;
  const unsigned char* Bbase = Bs + l * 16;
#pragma unroll
  for (int kc = 0; kc < 4; kc++) {
    bf16x8 af = *(const bf16x8*)(Abase + kc * 64);
#pragma unroll
    for (int nt = 0; nt < 8; nt++) {
      bf16x8 bfr = *(const bf16x8*)(Bbase + (kc * 8 + nt) * 1024);
      acc[nt] = __builtin_amdgcn_mfma_f32_16x16x32_bf16(af, bfr, acc[nt], 0, 0, 0);
    }
  }

  // --- epilogue: bias + relu + L2 norm (rows m' = q*4+r, col = nt*16+m) ---
  float ss[4] = {0.f, 0.f, 0.f, 0.f};
#pragma unroll
  for (int nt = 0; nt < 8; nt++) {
    float bj = b[nt * 16 + m];
#pragma unroll
    for (int r = 0; r < 4; r++) {
      float v = fmaxf(acc[nt][r] + bj, 0.0f);
      acc[nt][r] = v;
      ss[r] += v * v;
    }
  }
#pragma unroll
  for (int r = 0; r < 4; r++) {
    float s = ss[r];
    s += __shfl_xor(s, 1, 64);
    s += __shfl_xor(s, 2, 64);
    s += __shfl_xor(s, 4, 64);
    s += __shfl_xor(s, 8, 64);
    ss[r] = 1.0f / fmaxf(sqrtf(s), 1e-12f);
  }
  __syncthreads();   // everyone done reading A/B before overwriting A region
#pragma unroll
  for (int nt = 0; nt < 8; nt++) {
#pragma unroll
    for (int r = 0; r < 4; r++) {
      unsigned short hv = f2bf(acc[nt][r] * ss[r]);
      *(unsigned short*)(As + (w * 16 + q * 4 + r) * 272 + (nt * 16 + m) * 2) = hv;
    }
  }
  __syncthreads();
  // --- coalesced copy-out: 64 rows x 256 B ---
  int rem = N_NODES - node0; if (rem > 64) rem = 64;
  for (int i = tid; i < 1024; i += 256) {
    int row = i >> 4, seg = i & 15;
    if (row < rem) {
      uint4 vv = *(const uint4*)(As + row * 272 + seg * 16);
      *(uint4*)((unsigned char*)outH + (size_t)(node0 + row) * 256 + seg * 16) = vv;
    }
  }
}

// ===========================================================================
// Layer-2 projection via MFMA: y = H @ W2 (128 -> 16), fp32 out.
// A-frags straight from global H (16B/lane), B-frags from packed W2.
// ===========================================================================
__global__ __launch_bounds__(256) void proj16_mfma(
    const unsigned char* __restrict__ Hb, const unsigned char* __restrict__ pW2,
    float* __restrict__ y) {
  int tid = threadIdx.x;
  int node0 = blockIdx.x * 64;
  int w = tid >> 6, l = tid & 63;
  int m = l & 15, q = l >> 4;
  int row = node0 + w * 16 + m;
  int crow = row < N_NODES ? row : N_NODES - 1;

  f32x4 acc = (f32x4){0.f, 0.f, 0.f, 0.f};
#pragma unroll
  for (int kc = 0; kc < 4; kc++) {
    bf16x8 af = *(const bf16x8*)(Hb + (size_t)crow * 256 + kc * 64 + q * 16);
    bf16x8 bfr = *(const bf16x8*)(pW2 + (kc * 64 + l) * 16);
    acc = __builtin_amdgcn_mfma_f32_16x16x32_bf16(af, bfr, acc, 0, 0, 0);
  }
#pragma unroll
  for (int r = 0; r < 4; r++) {
    int orow = node0 + w * 16 + q * 4 + r;
    if (orow < N_NODES) y[(size_t)orow * ODIM + m] = acc[r];
  }
}

// ===========================================================================
// Aggregate 16-dim y rows via CSR (no weights). Wave = 4 edge-quarters x 16 f.
// ===========================================================================
__global__ __launch_bounds__(256) void gather16_kernel(
    const float* __restrict__ y, const int* __restrict__ row_ptr,
    const int2* __restrict__ ep, float* __restrict__ aggy) {
  int lane = threadIdx.x & 63;
  int node = blockIdx.x * 4 + (threadIdx.x >> 6);
  if (node >= N_NODES) return;
  int f = lane & 15, eq = lane >> 4;
  int a = row_ptr[node], bnd = row_ptr[node + 1];
  float acc = 0.0f;
  int j = a + eq;
  for (; j + 8 <= bnd; j += 8) {
    int s0 = ep[j].x, s1 = ep[j + 4].x;
    float v0 = y[(size_t)s0 * ODIM + f];
    float v1 = y[(size_t)s1 * ODIM + f];
    acc += v0 + v1;
  }
  for (; j < bnd; j += 4) acc += y[(size_t)ep[j].x * ODIM + f];
  acc += __shfl_xor(acc, 16, 64);
  acc += __shfl_xor(acc, 32, 64);
  if (eq == 0) aggy[(size_t)node * ODIM + f] = acc;
}

// logits = relu((1+eps)*y + aggy + b); probs = softmax(logits).
__global__ __launch_bounds__(256) void final16_kernel(
    const float* __restrict__ y, const float* __restrict__ aggy,
    const float* __restrict__ b, const float* __restrict__ eps_p,
    float* __restrict__ out_logits, float* __restrict__ out_probs) {
  int tid = threadIdx.x;
  int j = tid & 15, ng = tid >> 4;
  int node = blockIdx.x * 16 + ng;
  float epf = 1.0f + *eps_p;
  size_t idx = (size_t)node * ODIM + j;
  float logit = fmaxf(fmaf(epf, y[idx], aggy[idx]) + b[j], 0.0f);

  float mx = logit;
#pragma unroll
  for (int mm = 8; mm >= 1; mm >>= 1) mx = fmaxf(mx, __shfl_xor(mx, mm, 16));
  float e = __expf(logit - mx);
  float ssum = e;
#pragma unroll
  for (int mm = 8; mm >= 1; mm >>= 1) ssum += __shfl_xor(ssum, mm, 16);
  out_logits[idx] = logit;
  out_probs[idx] = e / ssum;
}

// ===========================================================================
extern "C" void kernel_launch(void* const* d_in, const int* in_sizes, int n_in,
                              void* d_out, int out_size, void* d_ws, size_t ws_size,
                              hipStream_t stream) {
  const float* x = (const float*)d_in[0];
  const int* ei = (const int*)d_in[1];       // int64 in reference -> int32 on device
  const float* ew = (const float*)d_in[2];
  const float* W0 = (const float*)d_in[3];
  const float* b0 = (const float*)d_in[4];
  const float* e0 = (const float*)d_in[5];
  const float* W1 = (const float*)d_in[6];
  const float* b1 = (const float*)d_in[7];
  const float* e1 = (const float*)d_in[8];
  const float* W2 = (const float*)d_in[9];
  const float* b2 = (const float*)d_in[10];
  const float* e2 = (const float*)d_in[11];
  float* out = (float*)d_out;

  const int* srcp = ei;
  const int* dstp = ei + N_EDGES;

  // ---- workspace layout (~90.6 MB; 102.4 MB proven available) ----
  char* ws = (char*)d_ws;
  size_t off = 0;
  uint32* Agg = (uint32*)(ws + off);  off += (size_t)N_NODES * DIM * 2;   // 25.6 MB bf16 agg (later: y + aggy)
  uint32* Xb  = (uint32*)(ws + off);  off += (size_t)N_NODES * DIM * 2;   // 25.6 MB bf16 x
  uint32* H   = (uint32*)(ws + off);  off += (size_t)N_NODES * DIM * 2;   // 25.6 MB bf16 hidden
  int2* epack = (int2*)(ws + off);    off += (size_t)N_EDGES * 8;         // 12.8 MB
  int* row_ptr = (int*)(ws + off);    off += (size_t)(N_NODES + 16) * 4;
  int* cursor  = (int*)(ws + off);    off += (size_t)(N_NODES + 16) * 4;
  int* blockSums = (int*)(ws + off);  off += 1024;
  unsigned short* pW0 = (unsigned short*)(ws + off); off += 32768;
  unsigned short* pW1 = (unsigned short*)(ws + off); off += 32768;
  unsigned short* pW2 = (unsigned short*)(ws + off); off += 4096;

  float* y = (float*)Agg;                          // 6.4 MB, after agg is dead
  float* aggy = y + (size_t)N_NODES * ODIM;        // 6.4 MB

  // ---- independent prep: cast x, pack weights ----
  cast_x_kernel<<<(N_NODES * (DIM / 2) + 255) / 256, 256, 0, stream>>>(
      (const float2*)x, Xb);
  packW128_kernel<<<64, 256, 0, stream>>>(W0, pW0);
  packW128_kernel<<<64, 256, 0, stream>>>(W1, pW1);
  packW16_kernel<<<8, 256, 0, stream>>>(W2, pW2);

  // ---- build CSR (dst-bucketed) ----
  hipMemsetAsync(cursor, 0, N_NODES * sizeof(int), stream);
  hist_kernel<<<N_EDGES / 256, 256, 0, stream>>>(dstp, cursor);
  scan1_kernel<<<SCAN_BLOCKS, 256, 0, stream>>>(cursor, row_ptr, blockSums);
  scan2_kernel<<<1, 128, 0, stream>>>(blockSums);
  scan3_kernel<<<SCAN_BLOCKS, 256, 0, stream>>>(row_ptr, blockSums, cursor);
  fill_kernel<<<N_EDGES / 256, 256, 0, stream>>>(srcp, dstp, ew, cursor, epack);

  int ggrid = (N_NODES + 3) / 4;       // 25000
  int mgrid = (N_NODES + 63) / 64;     // 1563
  int fgrid = N_NODES / 16;            // 6250

  // layer 0: agg0 = gather(Xb); H = mlp(Xb, agg0, W0)
  gather_bf16<<<ggrid, 256, 0, stream>>>(Xb, row_ptr, epack, Agg);
  gin_mlp_mfma<<<mgrid, 256, 0, stream>>>(Xb, Agg, (const unsigned char*)pW0,
                                          b0, e0, H);
  // layer 1: agg1 = gather(H); H = mlp(H, agg1, W1)  (in-place safe)
  gather_bf16<<<ggrid, 256, 0, stream>>>(H, row_ptr, epack, Agg);
  gin_mlp_mfma<<<mgrid, 256, 0, stream>>>(H, Agg, (const unsigned char*)pW1,
                                          b1, e1, H);
  // layer 2 (projection-first, unweighted): y = H @ W2; aggy = gather16(y)
  proj16_mfma<<<mgrid, 256, 0, stream>>>((const unsigned char*)H,
                                         (const unsigned char*)pW2, y);
  gather16_kernel<<<ggrid, 256, 0, stream>>>(y, row_ptr, epack, aggy);
  final16_kernel<<<fgrid, 256, 0, stream>>>(y, aggy, b2, e2,
                                            out, out + (size_t)N_NODES * ODIM);
}

// Round 5
// 487.312 us; speedup vs baseline: 4.6638x; 1.1490x over previous
//
#include <hip/hip_runtime.h>
#include <hip/hip_bf16.h>

#define N_NODES 100000
#define N_EDGES 1600000
#define DIM 128
#define ODIM 16
#define SCAN_CHUNK 1024
#define SCAN_BLOCKS 98   // 98*1024 >= N_NODES
#define NB 391           // coarse buckets: node >> 8
#define PCHUNK 3200      // edges per coarse-partition block
#define PBLK 500         // 500*3200 = 1.6M exactly
#define FCAP 8192        // fine-sort LDS capacity (bucket mean 4092, std 64)

typedef unsigned int uint32;
typedef float f32x4 __attribute__((ext_vector_type(4)));
typedef short bf16x8 __attribute__((ext_vector_type(8)));

static __device__ __forceinline__ float bflo(uint32 p) { return __uint_as_float(p << 16); }
static __device__ __forceinline__ float bfhi(uint32 p) { return __uint_as_float(p & 0xFFFF0000u); }
static __device__ __forceinline__ unsigned short f2bf(float f) {
  __hip_bfloat16 h = __float2bfloat16(f);
  return *reinterpret_cast<unsigned short*>(&h);
}
static __device__ __forceinline__ uint32 pk2bf(float a, float b) {
  return (uint32)f2bf(a) | ((uint32)f2bf(b) << 16);
}

// ===========================================================================
// Per-node histogram + exclusive scan -> row_ptr (unchanged pipeline).
// ===========================================================================
__global__ __launch_bounds__(256) void hist_kernel(
    const int* __restrict__ dst, int* __restrict__ counts) {
  int e = blockIdx.x * 256 + threadIdx.x;
  if (e < N_EDGES) atomicAdd(&counts[dst[e]], 1);
}

__global__ __launch_bounds__(256) void scan1_kernel(
    const int* __restrict__ counts, int* __restrict__ local_excl,
    int* __restrict__ blockSums) {
  __shared__ int ts[256];
  int t = threadIdx.x;
  int base = blockIdx.x * SCAN_CHUNK + t * 4;
  int v[4];
#pragma unroll
  for (int j = 0; j < 4; j++) v[j] = (base + j < N_NODES) ? counts[base + j] : 0;
  int s = v[0] + v[1] + v[2] + v[3];
  ts[t] = s;
  __syncthreads();
  for (int off = 1; off < 256; off <<= 1) {
    int a = (t >= off) ? ts[t - off] : 0;
    __syncthreads();
    ts[t] += a;
    __syncthreads();
  }
  if (t == 255) blockSums[blockIdx.x] = ts[255];
  int run = ts[t] - s;
#pragma unroll
  for (int j = 0; j < 4; j++) {
    if (base + j < N_NODES) local_excl[base + j] = run;
    run += v[j];
  }
}

__global__ __launch_bounds__(128) void scan2_kernel(int* __restrict__ blockSums) {
  __shared__ int bs[128];
  int t = threadIdx.x;
  int orig = (t < SCAN_BLOCKS) ? blockSums[t] : 0;
  bs[t] = orig;
  __syncthreads();
  for (int off = 1; off < 128; off <<= 1) {
    int a = (t >= off) ? bs[t - off] : 0;
    __syncthreads();
    bs[t] += a;
    __syncthreads();
  }
  if (t < SCAN_BLOCKS) blockSums[t] = bs[t] - orig;
}

__global__ __launch_bounds__(256) void scan3_kernel(
    int* __restrict__ row_ptr, const int* __restrict__ blockSums) {
  int t = threadIdx.x;
  int base = blockIdx.x * SCAN_CHUNK + t * 4;
  int off = blockSums[blockIdx.x];
#pragma unroll
  for (int j = 0; j < 4; j++) {
    if (base + j < N_NODES) row_ptr[base + j] += off;
  }
  if (blockIdx.x == 0 && t == 0) row_ptr[N_NODES] = N_EDGES;
}

// bcur[b] = row_ptr[b<<8] : coarse bucket write cursors.
__global__ __launch_bounds__(256) void bucket_init_kernel(
    const int* __restrict__ row_ptr, int* __restrict__ bcur) {
  int b = blockIdx.x * 256 + threadIdx.x;
  if (b < NB) bcur[b] = row_ptr[b << 8];
}

// ===========================================================================
// Coarse partition: bin edges by (dst>>8) with LDS staging, flush run-wise
// coalesced. Entry: x = src | ((dst&255)<<20), y = bits(weight).
// ===========================================================================
__global__ __launch_bounds__(256) void coarse_partition_kernel(
    const int* __restrict__ src, const int* __restrict__ dst,
    const float* __restrict__ ew, int* __restrict__ bcur,
    int2* __restrict__ epack) {
  __shared__ int hist[NB];
  __shared__ int base_a[NB];
  __shared__ int lcur_a[NB];
  __shared__ int gbase_a[NB];
  __shared__ int2 stg[PCHUNK];
  __shared__ int gpos[PCHUNK];

  int tid = threadIdx.x;
  int e0 = blockIdx.x * PCHUNK;

  for (int i = tid; i < NB; i += 256) hist[i] = 0;
  __syncthreads();
  for (int i = tid; i < PCHUNK; i += 256) atomicAdd(&hist[dst[e0 + i] >> 8], 1);
  __syncthreads();

  // wave-0 exclusive scan over NB buckets
  if (tid < 64) {
    int run = 0;
#pragma unroll
    for (int c = 0; c < 7; c++) {
      int idx = c * 64 + tid;
      int v = (idx < NB) ? hist[idx] : 0;
      int incl = v;
#pragma unroll
      for (int off = 1; off < 64; off <<= 1) {
        int tv = __shfl_up(incl, off, 64);
        if (tid >= off) incl += tv;
      }
      if (idx < NB) base_a[idx] = run + incl - v;
      run += __shfl(incl, 63, 64);
    }
  }
  __syncthreads();
  for (int i = tid; i < NB; i += 256) {
    int c = hist[i];
    gbase_a[i] = (c > 0) ? atomicAdd(&bcur[i], c) : 0;
    lcur_a[i] = base_a[i];
  }
  __syncthreads();

  for (int i = tid; i < PCHUNK; i += 256) {
    int e = e0 + i;
    int s = src[e], d = dst[e];
    float w = ew[e];
    int b = d >> 8;
    int pos = atomicAdd(&lcur_a[b], 1);
    stg[pos] = make_int2(s | ((d & 255) << 20), __float_as_int(w));
    gpos[pos] = gbase_a[b] + (pos - base_a[b]);
  }
  __syncthreads();
  for (int i = tid; i < PCHUNK; i += 256) epack[gpos[i]] = stg[i];
}

// ===========================================================================
// Fine sort (in-place): one block per coarse bucket; load bucket to LDS,
// scatter to exact per-node CSR positions (region is L2-resident ~34 KB).
// Output entry: x = src, y = weight bits.
// ===========================================================================
__global__ __launch_bounds__(256) void fine_sort_kernel(
    const int* __restrict__ row_ptr, int2* __restrict__ epack) {
  __shared__ int2 ebuf[FCAP];
  __shared__ int cur[256];
  int tid = threadIdx.x;
  int b = blockIdx.x;
  int node0 = b << 8;
  int hiNode = node0 + 256 < N_NODES ? node0 + 256 : N_NODES;
  int lo = row_ptr[node0], hi = row_ptr[hiNode];
  int n = hi - lo;
  if (n > FCAP) n = FCAP;   // statistically impossible (mean 4092, std 64)
  for (int i = tid; i < n; i += 256) ebuf[i] = epack[lo + i];
  if (node0 + tid < N_NODES) cur[tid] = row_ptr[node0 + tid];
  __syncthreads();
  for (int i = tid; i < n; i += 256) {
    int2 e = ebuf[i];
    int dlow = (e.x >> 20) & 255;
    int pos = atomicAdd(&cur[dlow], 1);
    epack[pos] = make_int2(e.x & 0xFFFFF, e.y);
  }
}

// ===========================================================================
// Cast x (f32, N x 128) -> packed bf16 pairs (N x 64 uints).
// ===========================================================================
__global__ __launch_bounds__(256) void cast_x_kernel(
    const float2* __restrict__ x2, uint32* __restrict__ Xu) {
  int i = blockIdx.x * 256 + threadIdx.x;
  if (i < N_NODES * (DIM / 2)) {
    float2 v = x2[i];
    Xu[i] = pk2bf(v.x, v.y);
  }
}

// ===========================================================================
// Pack W (f32 K x N) into MFMA B-fragment order, bf16.
// ===========================================================================
__global__ __launch_bounds__(256) void packW128_kernel(
    const float* __restrict__ W, unsigned short* __restrict__ out) {
  int idx = blockIdx.x * 256 + threadIdx.x;          // 16384
  int j = idx & 7, lane = (idx >> 3) & 63, nt = (idx >> 9) & 7, kc = idx >> 12;
  int k = kc * 32 + (lane >> 4) * 8 + j;
  int n = nt * 16 + (lane & 15);
  out[idx] = f2bf(W[k * DIM + n]);
}

__global__ __launch_bounds__(256) void packW16_kernel(
    const float* __restrict__ W, unsigned short* __restrict__ out) {
  int idx = blockIdx.x * 256 + threadIdx.x;          // 2048
  if (idx >= 2048) return;
  int j = idx & 7, lane = (idx >> 3) & 63, kc = idx >> 9;
  int k = kc * 32 + (lane >> 4) * 8 + j;
  int n = lane & 15;
  out[idx] = f2bf(W[k * ODIM + n]);
}

// ===========================================================================
// Gather aggregation over CSR, bf16 in / bf16 out. Wave per node, x4 unroll.
// ===========================================================================
__global__ __launch_bounds__(256) void gather_bf16(
    const uint32* __restrict__ hu, const int* __restrict__ row_ptr,
    const int2* __restrict__ ep, uint32* __restrict__ aggu) {
  int lane = threadIdx.x & 63;
  int node = blockIdx.x * 4 + (threadIdx.x >> 6);
  if (node >= N_NODES) return;
  int a = row_ptr[node], bnd = row_ptr[node + 1];
  float acc0 = 0.0f, acc1 = 0.0f;
  int j = a;
  for (; j + 4 <= bnd; j += 4) {
    int2 e0 = ep[j], e1 = ep[j + 1], e2 = ep[j + 2], e3 = ep[j + 3];
    uint32 p0 = hu[(size_t)e0.x * 64 + lane];
    uint32 p1 = hu[(size_t)e1.x * 64 + lane];
    uint32 p2 = hu[(size_t)e2.x * 64 + lane];
    uint32 p3 = hu[(size_t)e3.x * 64 + lane];
    float w0 = __int_as_float(e0.y), w1 = __int_as_float(e1.y);
    float w2 = __int_as_float(e2.y), w3 = __int_as_float(e3.y);
    acc0 = fmaf(w0, bflo(p0), acc0); acc1 = fmaf(w0, bfhi(p0), acc1);
    acc0 = fmaf(w1, bflo(p1), acc0); acc1 = fmaf(w1, bfhi(p1), acc1);
    acc0 = fmaf(w2, bflo(p2), acc0); acc1 = fmaf(w2, bfhi(p2), acc1);
    acc0 = fmaf(w3, bflo(p3), acc0); acc1 = fmaf(w3, bfhi(p3), acc1);
  }
  for (; j < bnd; j++) {
    int2 e0 = ep[j];
    uint32 p0 = hu[(size_t)e0.x * 64 + lane];
    float w0 = __int_as_float(e0.y);
    acc0 = fmaf(w0, bflo(p0), acc0); acc1 = fmaf(w0, bfhi(p0), acc1);
  }
  aggu[(size_t)node * 64 + lane] = pk2bf(acc0, acc1);
}

// ===========================================================================
// Fused GIN MLP via MFMA (bf16), 64 nodes x 128 outs per block.
// ===========================================================================
__global__ __launch_bounds__(256) void gin_mlp_mfma(
    const uint32* Xu, const uint32* __restrict__ Au,
    const unsigned char* __restrict__ pW, const float* __restrict__ b,
    const float* __restrict__ eps_p, uint32* outH) {
  __shared__ __align__(16) unsigned char smem[17408 + 32768];
  unsigned char* As = smem;
  unsigned char* Bs = smem + 17408;

  int tid = threadIdx.x;
  int node0 = blockIdx.x * 64;
  float epf = 1.0f + *eps_p;

  for (int i = tid; i < 64 * 64; i += 256) {
    int n = i >> 6, fp = i & 63;
    int node = node0 + n;
    int cn = node < N_NODES ? node : N_NODES - 1;
    size_t idx = (size_t)cn * 64 + fp;
    uint32 xv = Xu[idx], av = Au[idx];
    float u0 = fmaf(epf, bflo(xv), bflo(av));
    float u1 = fmaf(epf, bfhi(xv), bfhi(av));
    *(uint32*)(As + n * 272 + fp * 4) = pk2bf(u0, u1);
  }
  {
    const uint4* Wp = (const uint4*)pW;
    uint4* Bl = (uint4*)Bs;
    for (int i = tid; i < 2048; i += 256) Bl[i] = Wp[i];
  }
  __syncthreads();

  int w = tid >> 6, l = tid & 63;
  int m = l & 15, q = l >> 4;

  f32x4 acc[8];
#pragma unroll
  for (int nt = 0; nt < 8; nt++) acc[nt] = (f32x4){0.f, 0.f, 0.f, 0.f};

  const unsigned char* Abase = As + (w * 16 + m) * 272 + q * 16;
  const unsigned char* Bbase = Bs + l * 16;
#pragma unroll
  for (int kc = 0; kc < 4; kc++) {
    bf16x8 af = *(const bf16x8*)(Abase + kc * 64);
#pragma unroll
    for (int nt = 0; nt < 8; nt++) {
      bf16x8 bfr = *(const bf16x8*)(Bbase + (kc * 8 + nt) * 1024);
      acc[nt] = __builtin_amdgcn_mfma_f32_16x16x32_bf16(af, bfr, acc[nt], 0, 0, 0);
    }
  }

  float ss[4] = {0.f, 0.f, 0.f, 0.f};
#pragma unroll
  for (int nt = 0; nt < 8; nt++) {
    float bj = b[nt * 16 + m];
#pragma unroll
    for (int r = 0; r < 4; r++) {
      float v = fmaxf(acc[nt][r] + bj, 0.0f);
      acc[nt][r] = v;
      ss[r] += v * v;
    }
  }
#pragma unroll
  for (int r = 0; r < 4; r++) {
    float s = ss[r];
    s += __shfl_xor(s, 1, 64);
    s += __shfl_xor(s, 2, 64);
    s += __shfl_xor(s, 4, 64);
    s += __shfl_xor(s, 8, 64);
    ss[r] = 1.0f / fmaxf(sqrtf(s), 1e-12f);
  }
  __syncthreads();
#pragma unroll
  for (int nt = 0; nt < 8; nt++) {
#pragma unroll
    for (int r = 0; r < 4; r++) {
      unsigned short hv = f2bf(acc[nt][r] * ss[r]);
      *(unsigned short*)(As + (w * 16 + q * 4 + r) * 272 + (nt * 16 + m) * 2) = hv;
    }
  }
  __syncthreads();
  int rem = N_NODES - node0; if (rem > 64) rem = 64;
  for (int i = tid; i < 1024; i += 256) {
    int row = i >> 4, seg = i & 15;
    if (row < rem) {
      uint4 vv = *(const uint4*)(As + row * 272 + seg * 16);
      *(uint4*)((unsigned char*)outH + (size_t)(node0 + row) * 256 + seg * 16) = vv;
    }
  }
}

// ===========================================================================
// Layer-2 projection via MFMA: y = H @ W2 (128 -> 16), fp32 out.
// ===========================================================================
__global__ __launch_bounds__(256) void proj16_mfma(
    const unsigned char* __restrict__ Hb, const unsigned char* __restrict__ pW2,
    float* __restrict__ y) {
  int tid = threadIdx.x;
  int node0 = blockIdx.x * 64;
  int w = tid >> 6, l = tid & 63;
  int m = l & 15, q = l >> 4;
  int row = node0 + w * 16 + m;
  int crow = row < N_NODES ? row : N_NODES - 1;

  f32x4 acc = (f32x4){0.f, 0.f, 0.f, 0.f};
#pragma unroll
  for (int kc = 0; kc < 4; kc++) {
    bf16x8 af = *(const bf16x8*)(Hb + (size_t)crow * 256 + kc * 64 + q * 16);
    bf16x8 bfr = *(const bf16x8*)(pW2 + (kc * 64 + l) * 16);
    acc = __builtin_amdgcn_mfma_f32_16x16x32_bf16(af, bfr, acc, 0, 0, 0);
  }
#pragma unroll
  for (int r = 0; r < 4; r++) {
    int orow = node0 + w * 16 + q * 4 + r;
    if (orow < N_NODES) y[(size_t)orow * ODIM + m] = acc[r];
  }
}

// ===========================================================================
// Fused: aggy = gather16(y); logits = relu((1+eps)*y + aggy + b);
// probs = softmax. Wave per node (4/block); quarters split the edge list.
// ===========================================================================
__global__ __launch_bounds__(256) void gather16_final_kernel(
    const float* __restrict__ y, const int* __restrict__ row_ptr,
    const int2* __restrict__ ep, const float* __restrict__ b,
    const float* __restrict__ eps_p, float* __restrict__ out_logits,
    float* __restrict__ out_probs) {
  int lane = threadIdx.x & 63;
  int node = blockIdx.x * 4 + (threadIdx.x >> 6);
  if (node >= N_NODES) return;
  int f = lane & 15, eq = lane >> 4;
  int a = row_ptr[node], bnd = row_ptr[node + 1];
  float acc = 0.0f;
  int j = a + eq;
  for (; j + 8 <= bnd; j += 8) {
    int s0 = ep[j].x, s1 = ep[j + 4].x;
    acc += y[(size_t)s0 * ODIM + f] + y[(size_t)s1 * ODIM + f];
  }
  for (; j < bnd; j += 4) acc += y[(size_t)ep[j].x * ODIM + f];
  acc += __shfl_xor(acc, 16, 64);
  acc += __shfl_xor(acc, 32, 64);
  if (eq == 0) {
    float epf = 1.0f + *eps_p;
    size_t idx = (size_t)node * ODIM + f;
    float logit = fmaxf(fmaf(epf, y[idx], acc) + b[f], 0.0f);
    float mx = logit;
#pragma unroll
    for (int mm = 8; mm >= 1; mm >>= 1) mx = fmaxf(mx, __shfl_xor(mx, mm, 16));
    float e = __expf(logit - mx);
    float ssum = e;
#pragma unroll
    for (int mm = 8; mm >= 1; mm >>= 1) ssum += __shfl_xor(ssum, mm, 16);
    out_logits[idx] = logit;
    out_probs[idx] = e / ssum;
  }
}

// ===========================================================================
extern "C" void kernel_launch(void* const* d_in, const int* in_sizes, int n_in,
                              void* d_out, int out_size, void* d_ws, size_t ws_size,
                              hipStream_t stream) {
  const float* x = (const float*)d_in[0];
  const int* ei = (const int*)d_in[1];       // int64 in reference -> int32 on device
  const float* ew = (const float*)d_in[2];
  const float* W0 = (const float*)d_in[3];
  const float* b0 = (const float*)d_in[4];
  const float* e0 = (const float*)d_in[5];
  const float* W1 = (const float*)d_in[6];
  const float* b1 = (const float*)d_in[7];
  const float* e1 = (const float*)d_in[8];
  const float* W2 = (const float*)d_in[9];
  const float* b2 = (const float*)d_in[10];
  const float* e2 = (const float*)d_in[11];
  float* out = (float*)d_out;

  const int* srcp = ei;
  const int* dstp = ei + N_EDGES;

  // ---- workspace layout (~90.6 MB; 102.4 MB proven available) ----
  char* ws = (char*)d_ws;
  size_t off = 0;
  uint32* Agg = (uint32*)(ws + off);  off += (size_t)N_NODES * DIM * 2;   // 25.6 MB
  uint32* Xb  = (uint32*)(ws + off);  off += (size_t)N_NODES * DIM * 2;   // 25.6 MB
  uint32* H   = (uint32*)(ws + off);  off += (size_t)N_NODES * DIM * 2;   // 25.6 MB
  int2* epack = (int2*)(ws + off);    off += (size_t)N_EDGES * 8;         // 12.8 MB
  int* row_ptr = (int*)(ws + off);    off += (size_t)(N_NODES + 16) * 4;
  int* counts  = (int*)(ws + off);    off += (size_t)(N_NODES + 16) * 4;
  int* blockSums = (int*)(ws + off);  off += 1024;
  int* bcur    = (int*)(ws + off);    off += 2048;
  unsigned short* pW0 = (unsigned short*)(ws + off); off += 32768;
  unsigned short* pW1 = (unsigned short*)(ws + off); off += 32768;
  unsigned short* pW2 = (unsigned short*)(ws + off); off += 4096;

  float* y = (float*)Agg;   // 6.4 MB, after agg is dead

  // ---- independent prep: cast x, pack weights ----
  cast_x_kernel<<<(N_NODES * (DIM / 2) + 255) / 256, 256, 0, stream>>>(
      (const float2*)x, Xb);
  packW128_kernel<<<64, 256, 0, stream>>>(W0, pW0);
  packW128_kernel<<<64, 256, 0, stream>>>(W1, pW1);
  packW16_kernel<<<8, 256, 0, stream>>>(W2, pW2);

  // ---- build CSR: hist -> scan -> coarse partition -> fine sort ----
  hipMemsetAsync(counts, 0, N_NODES * sizeof(int), stream);
  hist_kernel<<<N_EDGES / 256, 256, 0, stream>>>(dstp, counts);
  scan1_kernel<<<SCAN_BLOCKS, 256, 0, stream>>>(counts, row_ptr, blockSums);
  scan2_kernel<<<1, 128, 0, stream>>>(blockSums);
  scan3_kernel<<<SCAN_BLOCKS, 256, 0, stream>>>(row_ptr, blockSums);
  bucket_init_kernel<<<2, 256, 0, stream>>>(row_ptr, bcur);
  coarse_partition_kernel<<<PBLK, 256, 0, stream>>>(srcp, dstp, ew, bcur, epack);
  fine_sort_kernel<<<NB, 256, 0, stream>>>(row_ptr, epack);

  int ggrid = (N_NODES + 3) / 4;       // 25000
  int mgrid = (N_NODES + 63) / 64;     // 1563

  // layer 0: agg0 = gather(Xb); H = mlp(Xb, agg0, W0)
  gather_bf16<<<ggrid, 256, 0, stream>>>(Xb, row_ptr, epack, Agg);
  gin_mlp_mfma<<<mgrid, 256, 0, stream>>>(Xb, Agg, (const unsigned char*)pW0,
                                          b0, e0, H);
  // layer 1: agg1 = gather(H); H = mlp(H, agg1, W1)  (in-place safe)
  gather_bf16<<<ggrid, 256, 0, stream>>>(H, row_ptr, epack, Agg);
  gin_mlp_mfma<<<mgrid, 256, 0, stream>>>(H, Agg, (const unsigned char*)pW1,
                                          b1, e1, H);
  // layer 2 (projection-first, unweighted): y = H @ W2; fused gather+final
  proj16_mfma<<<mgrid, 256, 0, stream>>>((const unsigned char*)H,
                                         (const unsigned char*)pW2, y);
  gather16_final_kernel<<<ggrid, 256, 0, stream>>>(y, row_ptr, epack, b2, e2,
                                                   out, out + (size_t)N_NODES * ODIM);
}

// Round 8
// 413.801 us; speedup vs baseline: 5.4923x; 1.1776x over previous
//
#include <hip/hip_runtime.h>
#include <hip/hip_bf16.h>

#define N_NODES 100000
#define N_EDGES 1600000
#define DIM 128
#define ODIM 16
#define NB 391           // coarse buckets: node >> 8
#define PCHUNK 3200      // edges per partition/hist block
#define PBLK 500         // 500*3200 = 1.6M exactly
#define FCAP 6144        // fine-sort LDS capacity (bucket mean 4096, std 64 -> 32 sigma)

typedef unsigned int uint32;
typedef float f32x4 __attribute__((ext_vector_type(4)));
typedef short bf16x8 __attribute__((ext_vector_type(8)));

static __device__ __forceinline__ float bflo(uint32 p) { return __uint_as_float(p << 16); }
static __device__ __forceinline__ float bfhi(uint32 p) { return __uint_as_float(p & 0xFFFF0000u); }
static __device__ __forceinline__ unsigned short f2bf(float f) {
  __hip_bfloat16 h = __float2bfloat16(f);
  return *reinterpret_cast<unsigned short*>(&h);
}
static __device__ __forceinline__ uint32 pk2bf(float a, float b) {
  return (uint32)f2bf(a) | ((uint32)f2bf(b) << 16);
}

// ===========================================================================
// Coarse bucket histogram (LDS-aggregated) -> bcnt[NB].
// ===========================================================================
__global__ __launch_bounds__(256) void bucket_hist_kernel(
    const int* __restrict__ dst, int* __restrict__ bcnt) {
  __shared__ int h[NB];
  int tid = threadIdx.x;
  for (int i = tid; i < NB; i += 256) h[i] = 0;
  __syncthreads();
  int e0 = blockIdx.x * PCHUNK;
  for (int i = tid; i < PCHUNK; i += 256) atomicAdd(&h[dst[e0 + i] >> 8], 1);
  __syncthreads();
  for (int i = tid; i < NB; i += 256)
    if (h[i]) atomicAdd(&bcnt[i], h[i]);
}

// One block: exclusive scan of bcnt -> bbase, bcur.
__global__ __launch_bounds__(512) void bucket_scan_kernel(
    const int* __restrict__ bcnt, int* __restrict__ bbase,
    int* __restrict__ bcur) {
  __shared__ int sc[512];
  int t = threadIdx.x;
  int v = (t < NB) ? bcnt[t] : 0;
  sc[t] = v;
  __syncthreads();
  for (int off = 1; off < 512; off <<= 1) {
    int a = (t >= off) ? sc[t - off] : 0;
    __syncthreads();
    sc[t] += a;
    __syncthreads();
  }
  if (t < NB) {
    int base = sc[t] - v;
    bbase[t] = base;
    bcur[t] = base;
  }
}

// ===========================================================================
// Coarse partition: bin edges by (dst>>8) with LDS staging, flush run-wise
// coalesced. Entry: x = src | ((dst&255)<<20), y = bits(weight).
// ===========================================================================
__global__ __launch_bounds__(256) void coarse_partition_kernel(
    const int* __restrict__ src, const int* __restrict__ dst,
    const float* __restrict__ ew, int* __restrict__ bcur,
    int2* __restrict__ epack) {
  __shared__ int hist[NB];
  __shared__ int base_a[NB];
  __shared__ int lcur_a[NB];
  __shared__ int gbase_a[NB];
  __shared__ int2 stg[PCHUNK];
  __shared__ int gpos[PCHUNK];

  int tid = threadIdx.x;
  int e0 = blockIdx.x * PCHUNK;

  for (int i = tid; i < NB; i += 256) hist[i] = 0;
  __syncthreads();
  for (int i = tid; i < PCHUNK; i += 256) atomicAdd(&hist[dst[e0 + i] >> 8], 1);
  __syncthreads();

  // wave-0 exclusive scan over NB buckets
  if (tid < 64) {
    int run = 0;
#pragma unroll
    for (int c = 0; c < 7; c++) {
      int idx = c * 64 + tid;
      int v = (idx < NB) ? hist[idx] : 0;
      int incl = v;
#pragma unroll
      for (int off = 1; off < 64; off <<= 1) {
        int tv = __shfl_up(incl, off, 64);
        if (tid >= off) incl += tv;
      }
      if (idx < NB) base_a[idx] = run + incl - v;
      run += __shfl(incl, 63, 64);
    }
  }
  __syncthreads();
  for (int i = tid; i < NB; i += 256) {
    int c = hist[i];
    gbase_a[i] = (c > 0) ? atomicAdd(&bcur[i], c) : 0;
    lcur_a[i] = base_a[i];
  }
  __syncthreads();

  for (int i = tid; i < PCHUNK; i += 256) {
    int e = e0 + i;
    int s = src[e], d = dst[e];
    float w = ew[e];
    int b = d >> 8;
    int pos = atomicAdd(&lcur_a[b], 1);
    stg[pos] = make_int2(s | ((d & 255) << 20), __float_as_int(w));
    gpos[pos] = gbase_a[b] + (pos - base_a[b]);
  }
  __syncthreads();
  for (int i = tid; i < PCHUNK; i += 256) epack[gpos[i]] = stg[i];
}

// ===========================================================================
// Fine sort (in-place) + row_ptr build: one block per coarse bucket.
// Output entry: x = src, y = weight bits. LDS = 52.2 KB.
// ===========================================================================
__global__ __launch_bounds__(256) void fine_sort_kernel(
    const int* __restrict__ bbase, int2* __restrict__ epack,
    int* __restrict__ row_ptr) {
  __shared__ int2 ebuf[FCAP];
  __shared__ int hist[256];
  __shared__ int sc[256];
  __shared__ int cur[256];
  int tid = threadIdx.x;
  int b = blockIdx.x;
  int node0 = b << 8;
  int lo = bbase[b];
  int hi = (b == NB - 1) ? N_EDGES : bbase[b + 1];
  int n = hi - lo;
  if (n > FCAP) n = FCAP;   // statistically impossible (32 sigma)
  hist[tid] = 0;
  __syncthreads();
  for (int i = tid; i < n; i += 256) {
    int2 e = epack[lo + i];
    ebuf[i] = e;
    atomicAdd(&hist[(e.x >> 20) & 255], 1);
  }
  __syncthreads();
  sc[tid] = hist[tid];
  __syncthreads();
  for (int off = 1; off < 256; off <<= 1) {
    int a = (tid >= off) ? sc[tid - off] : 0;
    __syncthreads();
    sc[tid] += a;
    __syncthreads();
  }
  int rp = lo + sc[tid] - hist[tid];   // exclusive
  if (node0 + tid < N_NODES) row_ptr[node0 + tid] = rp;
  cur[tid] = rp;
  if (b == 0 && tid == 0) row_ptr[N_NODES] = N_EDGES;
  __syncthreads();
  for (int i = tid; i < n; i += 256) {
    int2 e = ebuf[i];
    int pos = atomicAdd(&cur[(e.x >> 20) & 255], 1);
    epack[pos] = make_int2(e.x & 0xFFFFF, e.y);
  }
}

// ===========================================================================
// Cast x (f32, N x 128) -> packed bf16 pairs (N x 64 uints).
// ===========================================================================
__global__ __launch_bounds__(256) void cast_x_kernel(
    const float2* __restrict__ x2, uint32* __restrict__ Xu) {
  int i = blockIdx.x * 256 + threadIdx.x;
  if (i < N_NODES * (DIM / 2)) {
    float2 v = x2[i];
    Xu[i] = pk2bf(v.x, v.y);
  }
}

// ===========================================================================
// Pack W (f32 K x N) into MFMA B-fragment order, bf16.
// ===========================================================================
__global__ __launch_bounds__(256) void packW128_kernel(
    const float* __restrict__ W, unsigned short* __restrict__ out) {
  int idx = blockIdx.x * 256 + threadIdx.x;          // 16384
  int j = idx & 7, lane = (idx >> 3) & 63, nt = (idx >> 9) & 7, kc = idx >> 12;
  int k = kc * 32 + (lane >> 4) * 8 + j;
  int n = nt * 16 + (lane & 15);
  out[idx] = f2bf(W[k * DIM + n]);
}

__global__ __launch_bounds__(256) void packW16_kernel(
    const float* __restrict__ W, unsigned short* __restrict__ out) {
  int idx = blockIdx.x * 256 + threadIdx.x;          // 2048
  if (idx >= 2048) return;
  int j = idx & 7, lane = (idx >> 3) & 63, kc = idx >> 9;
  int k = kc * 32 + (lane >> 4) * 8 + j;
  int n = lane & 15;
  out[idx] = f2bf(W[k * ODIM + n]);
}

// ===========================================================================
// Gather v2: 2 edges per wave-pass (lanes 0-31 edge j, 32-63 edge j+1),
// 8 B/lane row loads (4 features), x4 outer unroll = 8 rows in flight.
// ===========================================================================
__global__ __launch_bounds__(256) void gather_bf16(
    const uint32* __restrict__ hu, const int* __restrict__ row_ptr,
    const int2* __restrict__ ep, uint32* __restrict__ aggu) {
  int lane = threadIdx.x & 63;
  int node = blockIdx.x * 4 + (threadIdx.x >> 6);
  if (node >= N_NODES) return;
  int half = lane >> 5, l2 = lane & 31;
  int a = row_ptr[node], bnd = row_ptr[node + 1];
  float acc0 = 0.f, acc1 = 0.f, acc2 = 0.f, acc3 = 0.f;
  int j = a;
  for (; j + 8 <= bnd; j += 8) {
    int2 ea = ep[j + 0 + half];
    int2 eb = ep[j + 2 + half];
    int2 ec = ep[j + 4 + half];
    int2 ed = ep[j + 6 + half];
    uint2 pa = *(const uint2*)(hu + (size_t)ea.x * 64 + l2 * 2);
    uint2 pb = *(const uint2*)(hu + (size_t)eb.x * 64 + l2 * 2);
    uint2 pc = *(const uint2*)(hu + (size_t)ec.x * 64 + l2 * 2);
    uint2 pd = *(const uint2*)(hu + (size_t)ed.x * 64 + l2 * 2);
    float wa = __int_as_float(ea.y), wb = __int_as_float(eb.y);
    float wc = __int_as_float(ec.y), wd = __int_as_float(ed.y);
    acc0 = fmaf(wa, bflo(pa.x), acc0); acc1 = fmaf(wa, bfhi(pa.x), acc1);
    acc2 = fmaf(wa, bflo(pa.y), acc2); acc3 = fmaf(wa, bfhi(pa.y), acc3);
    acc0 = fmaf(wb, bflo(pb.x), acc0); acc1 = fmaf(wb, bfhi(pb.x), acc1);
    acc2 = fmaf(wb, bflo(pb.y), acc2); acc3 = fmaf(wb, bfhi(pb.y), acc3);
    acc0 = fmaf(wc, bflo(pc.x), acc0); acc1 = fmaf(wc, bfhi(pc.x), acc1);
    acc2 = fmaf(wc, bflo(pc.y), acc2); acc3 = fmaf(wc, bfhi(pc.y), acc3);
    acc0 = fmaf(wd, bflo(pd.x), acc0); acc1 = fmaf(wd, bfhi(pd.x), acc1);
    acc2 = fmaf(wd, bflo(pd.y), acc2); acc3 = fmaf(wd, bfhi(pd.y), acc3);
  }
  for (; j + 2 <= bnd; j += 2) {
    int2 e0 = ep[j + half];
    uint2 p0 = *(const uint2*)(hu + (size_t)e0.x * 64 + l2 * 2);
    float w0 = __int_as_float(e0.y);
    acc0 = fmaf(w0, bflo(p0.x), acc0); acc1 = fmaf(w0, bfhi(p0.x), acc1);
    acc2 = fmaf(w0, bflo(p0.y), acc2); acc3 = fmaf(w0, bfhi(p0.y), acc3);
  }
  if (j < bnd && half == 0) {
    int2 e0 = ep[j];
    uint2 p0 = *(const uint2*)(hu + (size_t)e0.x * 64 + l2 * 2);
    float w0 = __int_as_float(e0.y);
    acc0 = fmaf(w0, bflo(p0.x), acc0); acc1 = fmaf(w0, bfhi(p0.x), acc1);
    acc2 = fmaf(w0, bflo(p0.y), acc2); acc3 = fmaf(w0, bfhi(p0.y), acc3);
  }
  acc0 += __shfl_xor(acc0, 32, 64);
  acc1 += __shfl_xor(acc1, 32, 64);
  acc2 += __shfl_xor(acc2, 32, 64);
  acc3 += __shfl_xor(acc3, 32, 64);
  if (half == 0) {
    uint2 st = {pk2bf(acc0, acc1), pk2bf(acc2, acc3)};
    *(uint2*)(aggu + (size_t)node * 64 + l2 * 2) = st;
  }
}

// ===========================================================================
// Fused GIN MLP via MFMA (bf16), 64 nodes x 128 outs per block.
// FUSE_PROJ=1 additionally emits y = H_norm @ W2 (128->16, fp32) from the
// normalized tile already in LDS (W2 frags read straight from global, 4 KB).
// ===========================================================================
template <int FUSE_PROJ>
__global__ __launch_bounds__(256) void gin_mlp_mfma(
    const uint32* Xu, const uint32* __restrict__ Au,
    const unsigned char* __restrict__ pW, const float* __restrict__ b,
    const float* __restrict__ eps_p, uint32* outH,
    const unsigned char* __restrict__ pW2, float* __restrict__ y) {
  __shared__ __align__(16) unsigned char smem[17408 + 32768];
  unsigned char* As = smem;
  unsigned char* Bs = smem + 17408;

  int tid = threadIdx.x;
  int node0 = blockIdx.x * 64;
  float epf = 1.0f + *eps_p;

  for (int i = tid; i < 64 * 64; i += 256) {
    int n = i >> 6, fp = i & 63;
    int node = node0 + n;
    int cn = node < N_NODES ? node : N_NODES - 1;
    size_t idx = (size_t)cn * 64 + fp;
    uint32 xv = Xu[idx], av = Au[idx];
    float u0 = fmaf(epf, bflo(xv), bflo(av));
    float u1 = fmaf(epf, bfhi(xv), bfhi(av));
    *(uint32*)(As + n * 272 + fp * 4) = pk2bf(u0, u1);
  }
  {
    const uint4* Wp = (const uint4*)pW;
    uint4* Bl = (uint4*)Bs;
    for (int i = tid; i < 2048; i += 256) Bl[i] = Wp[i];
  }
  __syncthreads();

  int w = tid >> 6, l = tid & 63;
  int m = l & 15, q = l >> 4;

  f32x4 acc[8];
#pragma unroll
  for (int nt = 0; nt < 8; nt++) acc[nt] = (f32x4){0.f, 0.f, 0.f, 0.f};

  const unsigned char* Abase = As + (w * 16 + m) * 272 + q * 16;
  const unsigned char* Bbase = Bs + l * 16;
#pragma unroll
  for (int kc = 0; kc < 4; kc++) {
    bf16x8 af = *(const bf16x8*)(Abase + kc * 64);
#pragma unroll
    for (int nt = 0; nt < 8; nt++) {
      bf16x8 bfr = *(const bf16x8*)(Bbase + (kc * 8 + nt) * 1024);
      acc[nt] = __builtin_amdgcn_mfma_f32_16x16x32_bf16(af, bfr, acc[nt], 0, 0, 0);
    }
  }

  float ss[4] = {0.f, 0.f, 0.f, 0.f};
#pragma unroll
  for (int nt = 0; nt < 8; nt++) {
    float bj = b[nt * 16 + m];
#pragma unroll
    for (int r = 0; r < 4; r++) {
      float v = fmaxf(acc[nt][r] + bj, 0.0f);
      acc[nt][r] = v;
      ss[r] += v * v;
    }
  }
#pragma unroll
  for (int r = 0; r < 4; r++) {
    float s = ss[r];
    s += __shfl_xor(s, 1, 64);
    s += __shfl_xor(s, 2, 64);
    s += __shfl_xor(s, 4, 64);
    s += __shfl_xor(s, 8, 64);
    ss[r] = 1.0f / fmaxf(sqrtf(s), 1e-12f);
  }
  __syncthreads();
#pragma unroll
  for (int nt = 0; nt < 8; nt++) {
#pragma unroll
    for (int r = 0; r < 4; r++) {
      unsigned short hv = f2bf(acc[nt][r] * ss[r]);
      *(unsigned short*)(As + (w * 16 + q * 4 + r) * 272 + (nt * 16 + m) * 2) = hv;
    }
  }
  __syncthreads();
  int rem = N_NODES - node0; if (rem > 64) rem = 64;
  for (int i = tid; i < 1024; i += 256) {
    int row = i >> 4, seg = i & 15;
    if (row < rem) {
      uint4 vv = *(const uint4*)(As + row * 272 + seg * 16);
      *(uint4*)((unsigned char*)outH + (size_t)(node0 + row) * 256 + seg * 16) = vv;
    }
  }
  if (FUSE_PROJ) {
    f32x4 accy = (f32x4){0.f, 0.f, 0.f, 0.f};
#pragma unroll
    for (int kc = 0; kc < 4; kc++) {
      bf16x8 af = *(const bf16x8*)(Abase + kc * 64);   // normalized H tile
      bf16x8 bfr = *(const bf16x8*)(pW2 + (kc * 64 + l) * 16);
      accy = __builtin_amdgcn_mfma_f32_16x16x32_bf16(af, bfr, accy, 0, 0, 0);
    }
#pragma unroll
    for (int r = 0; r < 4; r++) {
      int orow = node0 + w * 16 + q * 4 + r;
      if (orow < N_NODES) y[(size_t)orow * ODIM + m] = accy[r];
    }
  }
}

// ===========================================================================
// Fused: aggy = gather16(y); logits = relu((1+eps)*y + aggy + b);
// probs = softmax. Wave per node (4/block); quarters split the edge list.
// ===========================================================================
__global__ __launch_bounds__(256) void gather16_final_kernel(
    const float* __restrict__ y, const int* __restrict__ row_ptr,
    const int2* __restrict__ ep, const float* __restrict__ b,
    const float* __restrict__ eps_p, float* __restrict__ out_logits,
    float* __restrict__ out_probs) {
  int lane = threadIdx.x & 63;
  int node = blockIdx.x * 4 + (threadIdx.x >> 6);
  if (node >= N_NODES) return;
  int f = lane & 15, eq = lane >> 4;
  int a = row_ptr[node], bnd = row_ptr[node + 1];
  float acc = 0.0f;
  int j = a + eq;
  for (; j + 8 <= bnd; j += 8) {
    int s0 = ep[j].x, s1 = ep[j + 4].x;
    acc += y[(size_t)s0 * ODIM + f] + y[(size_t)s1 * ODIM + f];
  }
  for (; j < bnd; j += 4) acc += y[(size_t)ep[j].x * ODIM + f];
  acc += __shfl_xor(acc, 16, 64);
  acc += __shfl_xor(acc, 32, 64);
  if (eq == 0) {
    float epf = 1.0f + *eps_p;
    size_t idx = (size_t)node * ODIM + f;
    float logit = fmaxf(fmaf(epf, y[idx], acc) + b[f], 0.0f);
    float mx = logit;
#pragma unroll
    for (int mm = 8; mm >= 1; mm >>= 1) mx = fmaxf(mx, __shfl_xor(mx, mm, 16));
    float e = __expf(logit - mx);
    float ssum = e;
#pragma unroll
    for (int mm = 8; mm >= 1; mm >>= 1) ssum += __shfl_xor(ssum, mm, 16);
    out_logits[idx] = logit;
    out_probs[idx] = e / ssum;
  }
}

// ===========================================================================
extern "C" void kernel_launch(void* const* d_in, const int* in_sizes, int n_in,
                              void* d_out, int out_size, void* d_ws, size_t ws_size,
                              hipStream_t stream) {
  const float* x = (const float*)d_in[0];
  const int* ei = (const int*)d_in[1];       // int64 in reference -> int32 on device
  const float* ew = (const float*)d_in[2];
  const float* W0 = (const float*)d_in[3];
  const float* b0 = (const float*)d_in[4];
  const float* e0 = (const float*)d_in[5];
  const float* W1 = (const float*)d_in[6];
  const float* b1 = (const float*)d_in[7];
  const float* e1 = (const float*)d_in[8];
  const float* W2 = (const float*)d_in[9];
  const float* b2 = (const float*)d_in[10];
  const float* e2 = (const float*)d_in[11];
  float* out = (float*)d_out;

  const int* srcp = ei;
  const int* dstp = ei + N_EDGES;

  // ---- workspace layout (~97 MB; 102.4 MB proven available) ----
  char* ws = (char*)d_ws;
  size_t off = 0;
  uint32* Agg = (uint32*)(ws + off);  off += (size_t)N_NODES * DIM * 2;   // 25.6 MB
  uint32* Xb  = (uint32*)(ws + off);  off += (size_t)N_NODES * DIM * 2;   // 25.6 MB
  uint32* H   = (uint32*)(ws + off);  off += (size_t)N_NODES * DIM * 2;   // 25.6 MB
  int2* epack = (int2*)(ws + off);    off += (size_t)N_EDGES * 8;         // 12.8 MB
  float* y    = (float*)(ws + off);   off += (size_t)N_NODES * ODIM * 4;  // 6.4 MB
  int* row_ptr = (int*)(ws + off);    off += (size_t)(N_NODES + 16) * 4;
  int* bcnt   = (int*)(ws + off);     off += 2048;
  int* bbase  = (int*)(ws + off);     off += 2048;
  int* bcur   = (int*)(ws + off);     off += 2048;
  unsigned short* pW0 = (unsigned short*)(ws + off); off += 32768;
  unsigned short* pW1 = (unsigned short*)(ws + off); off += 32768;
  unsigned short* pW2 = (unsigned short*)(ws + off); off += 4096;

  // ---- independent prep: cast x, pack weights ----
  cast_x_kernel<<<(N_NODES * (DIM / 2) + 255) / 256, 256, 0, stream>>>(
      (const float2*)x, Xb);
  packW128_kernel<<<64, 256, 0, stream>>>(W0, pW0);
  packW128_kernel<<<64, 256, 0, stream>>>(W1, pW1);
  packW16_kernel<<<8, 256, 0, stream>>>(W2, pW2);

  // ---- build CSR: bucket hist -> scan -> coarse partition -> fine sort ----
  hipMemsetAsync(bcnt, 0, NB * sizeof(int), stream);
  bucket_hist_kernel<<<PBLK, 256, 0, stream>>>(dstp, bcnt);
  bucket_scan_kernel<<<1, 512, 0, stream>>>(bcnt, bbase, bcur);
  coarse_partition_kernel<<<PBLK, 256, 0, stream>>>(srcp, dstp, ew, bcur, epack);
  fine_sort_kernel<<<NB, 256, 0, stream>>>(bbase, epack, row_ptr);

  int ggrid = (N_NODES + 3) / 4;       // 25000
  int mgrid = (N_NODES + 63) / 64;     // 1563

  // layer 0: agg0 = gather(Xb); H = mlp(Xb, agg0, W0)
  gather_bf16<<<ggrid, 256, 0, stream>>>(Xb, row_ptr, epack, Agg);
  gin_mlp_mfma<0><<<mgrid, 256, 0, stream>>>(Xb, Agg, (const unsigned char*)pW0,
                                             b0, e0, H, nullptr, nullptr);
  // layer 1 (+fused layer-2 projection): agg1 = gather(H); H,y = mlp(H, agg1)
  gather_bf16<<<ggrid, 256, 0, stream>>>(H, row_ptr, epack, Agg);
  gin_mlp_mfma<1><<<mgrid, 256, 0, stream>>>(H, Agg, (const unsigned char*)pW1,
                                             b1, e1, H,
                                             (const unsigned char*)pW2, y);
  // layer 2 tail: fused gather16 + bias/relu/softmax
  gather16_final_kernel<<<ggrid, 256, 0, stream>>>(y, row_ptr, epack, b2, e2,
                                                   out, out + (size_t)N_NODES * ODIM);
}

// Round 11
// 402.602 us; speedup vs baseline: 5.6451x; 1.0278x over previous
//
#include <hip/hip_runtime.h>
#include <hip/hip_bf16.h>

#define N_NODES 100000
#define N_EDGES 1600000
#define DIM 128
#define ODIM 16
#define NB 391           // coarse buckets: node >> 8
#define PCHUNK 3200      // edges per partition/hist block
#define PBLK 500         // 500*3200 = 1.6M exactly
#define FCAP 6144        // fine-sort LDS capacity (bucket mean 4096, std 64 -> 32 sigma)

typedef unsigned int uint32;
typedef float f32x4 __attribute__((ext_vector_type(4)));
typedef short bf16x8 __attribute__((ext_vector_type(8)));

static __device__ __forceinline__ float bflo(uint32 p) { return __uint_as_float(p << 16); }
static __device__ __forceinline__ float bfhi(uint32 p) { return __uint_as_float(p & 0xFFFF0000u); }
static __device__ __forceinline__ unsigned short f2bf(float f) {
  __hip_bfloat16 h = __float2bfloat16(f);
  return *reinterpret_cast<unsigned short*>(&h);
}
static __device__ __forceinline__ uint32 pk2bf(float a, float b) {
  return (uint32)f2bf(a) | ((uint32)f2bf(b) << 16);
}

// ===========================================================================
// Coarse bucket histogram (LDS-aggregated) -> bcnt[NB].
// ===========================================================================
__global__ __launch_bounds__(256) void bucket_hist_kernel(
    const int* __restrict__ dst, int* __restrict__ bcnt) {
  __shared__ int h[NB];
  int tid = threadIdx.x;
  for (int i = tid; i < NB; i += 256) h[i] = 0;
  __syncthreads();
  int e0 = blockIdx.x * PCHUNK;
  for (int i = tid; i < PCHUNK; i += 256) atomicAdd(&h[dst[e0 + i] >> 8], 1);
  __syncthreads();
  for (int i = tid; i < NB; i += 256)
    if (h[i]) atomicAdd(&bcnt[i], h[i]);
}

// One block: exclusive scan of bcnt -> bbase, bcur.
__global__ __launch_bounds__(512) void bucket_scan_kernel(
    const int* __restrict__ bcnt, int* __restrict__ bbase,
    int* __restrict__ bcur) {
  __shared__ int sc[512];
  int t = threadIdx.x;
  int v = (t < NB) ? bcnt[t] : 0;
  sc[t] = v;
  __syncthreads();
  for (int off = 1; off < 512; off <<= 1) {
    int a = (t >= off) ? sc[t - off] : 0;
    __syncthreads();
    sc[t] += a;
    __syncthreads();
  }
  if (t < NB) {
    int base = sc[t] - v;
    bbase[t] = base;
    bcur[t] = base;
  }
}

// ===========================================================================
// Coarse partition: bin edges by (dst>>8) with LDS staging, flush run-wise
// coalesced. Entry: x = src | ((dst&255)<<20), y = bits(weight).
// ===========================================================================
__global__ __launch_bounds__(256) void coarse_partition_kernel(
    const int* __restrict__ src, const int* __restrict__ dst,
    const float* __restrict__ ew, int* __restrict__ bcur,
    int2* __restrict__ epack) {
  __shared__ int hist[NB];
  __shared__ int base_a[NB];
  __shared__ int lcur_a[NB];
  __shared__ int gbase_a[NB];
  __shared__ int2 stg[PCHUNK];
  __shared__ int gpos[PCHUNK];

  int tid = threadIdx.x;
  int e0 = blockIdx.x * PCHUNK;

  for (int i = tid; i < NB; i += 256) hist[i] = 0;
  __syncthreads();
  for (int i = tid; i < PCHUNK; i += 256) atomicAdd(&hist[dst[e0 + i] >> 8], 1);
  __syncthreads();

  // wave-0 exclusive scan over NB buckets
  if (tid < 64) {
    int run = 0;
#pragma unroll
    for (int c = 0; c < 7; c++) {
      int idx = c * 64 + tid;
      int v = (idx < NB) ? hist[idx] : 0;
      int incl = v;
#pragma unroll
      for (int off = 1; off < 64; off <<= 1) {
        int tv = __shfl_up(incl, off, 64);
        if (tid >= off) incl += tv;
      }
      if (idx < NB) base_a[idx] = run + incl - v;
      run += __shfl(incl, 63, 64);
    }
  }
  __syncthreads();
  for (int i = tid; i < NB; i += 256) {
    int c = hist[i];
    gbase_a[i] = (c > 0) ? atomicAdd(&bcur[i], c) : 0;
    lcur_a[i] = base_a[i];
  }
  __syncthreads();

  for (int i = tid; i < PCHUNK; i += 256) {
    int e = e0 + i;
    int s = src[e], d = dst[e];
    float w = ew[e];
    int b = d >> 8;
    int pos = atomicAdd(&lcur_a[b], 1);
    stg[pos] = make_int2(s | ((d & 255) << 20), __float_as_int(w));
    gpos[pos] = gbase_a[b] + (pos - base_a[b]);
  }
  __syncthreads();
  for (int i = tid; i < PCHUNK; i += 256) epack[gpos[i]] = stg[i];
}

// ===========================================================================
// Fine sort (in-place) + row_ptr build: one block per coarse bucket.
// Output entry: x = src, y = weight bits. LDS = 52.2 KB.
// ===========================================================================
__global__ __launch_bounds__(256) void fine_sort_kernel(
    const int* __restrict__ bbase, int2* __restrict__ epack,
    int* __restrict__ row_ptr) {
  __shared__ int2 ebuf[FCAP];
  __shared__ int hist[256];
  __shared__ int sc[256];
  __shared__ int cur[256];
  int tid = threadIdx.x;
  int b = blockIdx.x;
  int node0 = b << 8;
  int lo = bbase[b];
  int hi = (b == NB - 1) ? N_EDGES : bbase[b + 1];
  int n = hi - lo;
  if (n > FCAP) n = FCAP;   // statistically impossible (32 sigma)
  hist[tid] = 0;
  __syncthreads();
  for (int i = tid; i < n; i += 256) {
    int2 e = epack[lo + i];
    ebuf[i] = e;
    atomicAdd(&hist[(e.x >> 20) & 255], 1);
  }
  __syncthreads();
  sc[tid] = hist[tid];
  __syncthreads();
  for (int off = 1; off < 256; off <<= 1) {
    int a = (tid >= off) ? sc[tid - off] : 0;
    __syncthreads();
    sc[tid] += a;
    __syncthreads();
  }
  int rp = lo + sc[tid] - hist[tid];   // exclusive
  if (node0 + tid < N_NODES) row_ptr[node0 + tid] = rp;
  cur[tid] = rp;
  if (b == 0 && tid == 0) row_ptr[N_NODES] = N_EDGES;
  __syncthreads();
  for (int i = tid; i < n; i += 256) {
    int2 e = ebuf[i];
    int pos = atomicAdd(&cur[(e.x >> 20) & 255], 1);
    epack[pos] = make_int2(e.x & 0xFFFFF, e.y);
  }
}

// ===========================================================================
// Cast x (f32, N x 128) -> packed bf16 pairs (N x 64 uints).
// ===========================================================================
__global__ __launch_bounds__(256) void cast_x_kernel(
    const float2* __restrict__ x2, uint32* __restrict__ Xu) {
  int i = blockIdx.x * 256 + threadIdx.x;
  if (i < N_NODES * (DIM / 2)) {
    float2 v = x2[i];
    Xu[i] = pk2bf(v.x, v.y);
  }
}

// ===========================================================================
// Pack W (f32 K x N) into MFMA B-fragment order, bf16.
// ===========================================================================
__global__ __launch_bounds__(256) void packW128_kernel(
    const float* __restrict__ W, unsigned short* __restrict__ out) {
  int idx = blockIdx.x * 256 + threadIdx.x;          // 16384
  int j = idx & 7, lane = (idx >> 3) & 63, nt = (idx >> 9) & 7, kc = idx >> 12;
  int k = kc * 32 + (lane >> 4) * 8 + j;
  int n = nt * 16 + (lane & 15);
  out[idx] = f2bf(W[k * DIM + n]);
}

__global__ __launch_bounds__(256) void packW16_kernel(
    const float* __restrict__ W, unsigned short* __restrict__ out) {
  int idx = blockIdx.x * 256 + threadIdx.x;          // 2048
  if (idx >= 2048) return;
  int j = idx & 7, lane = (idx >> 3) & 63, kc = idx >> 9;
  int k = kc * 32 + (lane >> 4) * 8 + j;
  int n = lane & 15;
  out[idx] = f2bf(W[k * ODIM + n]);
}

// ===========================================================================
// Gather v3 (standalone): wave per node, uint4 row loads (16 lanes/row),
// 4 edges/instruction (grp = lane>>4), x2 unroll = 8 rows in flight.
// 0.5 vmem instructions per edge. Lanes 0-15 write the bf16 agg row (uint4).
// ===========================================================================
__global__ __launch_bounds__(256) void gather_bf16(
    const uint32* __restrict__ hu, const int* __restrict__ row_ptr,
    const int2* __restrict__ ep, uint32* __restrict__ aggu) {
  int lane = threadIdx.x & 63;
  int node = blockIdx.x * 4 + (threadIdx.x >> 6);
  if (node >= N_NODES) return;
  int grp = lane >> 4, l4 = lane & 15;
  int a = row_ptr[node], bnd = row_ptr[node + 1];
  float acc[8];
#pragma unroll
  for (int k = 0; k < 8; k++) acc[k] = 0.f;

  auto pass4 = [&](int jj) {
    int2 e = ep[jj + grp];
    uint4 p = *(const uint4*)(hu + (size_t)e.x * 64 + l4 * 4);
    float wv = __int_as_float(e.y);
    acc[0] = fmaf(wv, bflo(p.x), acc[0]); acc[1] = fmaf(wv, bfhi(p.x), acc[1]);
    acc[2] = fmaf(wv, bflo(p.y), acc[2]); acc[3] = fmaf(wv, bfhi(p.y), acc[3]);
    acc[4] = fmaf(wv, bflo(p.z), acc[4]); acc[5] = fmaf(wv, bfhi(p.z), acc[5]);
    acc[6] = fmaf(wv, bflo(p.w), acc[6]); acc[7] = fmaf(wv, bfhi(p.w), acc[7]);
  };

  int j = a;
  for (; j + 8 <= bnd; j += 8) { pass4(j); pass4(j + 4); }
  if (j + 4 <= bnd) { pass4(j); j += 4; }
  if (j < bnd) {   // masked tail (<4 edges; bnd>=1 guaranteed here)
    int idx = j + grp;
    int vld = idx < bnd;
    int2 e = ep[vld ? idx : bnd - 1];
    uint4 p = *(const uint4*)(hu + (size_t)e.x * 64 + l4 * 4);
    float wv = vld ? __int_as_float(e.y) : 0.f;
    acc[0] = fmaf(wv, bflo(p.x), acc[0]); acc[1] = fmaf(wv, bfhi(p.x), acc[1]);
    acc[2] = fmaf(wv, bflo(p.y), acc[2]); acc[3] = fmaf(wv, bfhi(p.y), acc[3]);
    acc[4] = fmaf(wv, bflo(p.z), acc[4]); acc[5] = fmaf(wv, bfhi(p.z), acc[5]);
    acc[6] = fmaf(wv, bflo(p.w), acc[6]); acc[7] = fmaf(wv, bfhi(p.w), acc[7]);
  }
#pragma unroll
  for (int k = 0; k < 8; k++) {
    acc[k] += __shfl_xor(acc[k], 16, 64);
    acc[k] += __shfl_xor(acc[k], 32, 64);
  }
  if (lane < 16) {
    uint4 st = {pk2bf(acc[0], acc[1]), pk2bf(acc[2], acc[3]),
                pk2bf(acc[4], acc[5]), pk2bf(acc[6], acc[7])};
    *(uint4*)(aggu + (size_t)node * 64 + l4 * 4) = st;
  }
}

// ===========================================================================
// Fused GIN MLP via MFMA (bf16), 64 nodes x 128 outs per block (r8-proven).
// FUSE_PROJ=1 additionally emits y = H_norm @ W2 (128->16, fp32).
// ===========================================================================
template <int FUSE_PROJ>
__global__ __launch_bounds__(256) void gin_mlp_mfma(
    const uint32* Xu, const uint32* __restrict__ Au,
    const unsigned char* __restrict__ pW, const float* __restrict__ b,
    const float* __restrict__ eps_p, uint32* outH,
    const unsigned char* __restrict__ pW2, float* __restrict__ y) {
  __shared__ __align__(16) unsigned char smem[17408 + 32768];
  unsigned char* As = smem;
  unsigned char* Bs = smem + 17408;

  int tid = threadIdx.x;
  int node0 = blockIdx.x * 64;
  float epf = 1.0f + *eps_p;

  for (int i = tid; i < 64 * 64; i += 256) {
    int n = i >> 6, fp = i & 63;
    int node = node0 + n;
    int cn = node < N_NODES ? node : N_NODES - 1;
    size_t idx = (size_t)cn * 64 + fp;
    uint32 xv = Xu[idx], av = Au[idx];
    float u0 = fmaf(epf, bflo(xv), bflo(av));
    float u1 = fmaf(epf, bfhi(xv), bfhi(av));
    *(uint32*)(As + n * 272 + fp * 4) = pk2bf(u0, u1);
  }
  {
    const uint4* Wp = (const uint4*)pW;
    uint4* Bl = (uint4*)Bs;
    for (int i = tid; i < 2048; i += 256) Bl[i] = Wp[i];
  }
  __syncthreads();

  int w = tid >> 6, l = tid & 63;
  int m = l & 15, q = l >> 4;

  f32x4 acc[8];
#pragma unroll
  for (int nt = 0; nt < 8; nt++) acc[nt] = (f32x4){0.f, 0.f, 0.f, 0.f};

  const unsigned char* Abase = As + (w * 16 + m) * 272 + q * 16;
  const unsigned char* Bbase = Bs + l * 16;
#pragma unroll
  for (int kc = 0; kc < 4; kc++) {
    bf16x8 af = *(const bf16x8*)(Abase + kc * 64);
#pragma unroll
    for (int nt = 0; nt < 8; nt++) {
      bf16x8 bfr = *(const bf16x8*)(Bbase + (kc * 8 + nt) * 1024);
      acc[nt] = __builtin_amdgcn_mfma_f32_16x16x32_bf16(af, bfr, acc[nt], 0, 0, 0);
    }
  }

  float ss[4] = {0.f, 0.f, 0.f, 0.f};
#pragma unroll
  for (int nt = 0; nt < 8; nt++) {
    float bj = b[nt * 16 + m];
#pragma unroll
    for (int r = 0; r < 4; r++) {
      float v = fmaxf(acc[nt][r] + bj, 0.0f);
      acc[nt][r] = v;
      ss[r] += v * v;
    }
  }
#pragma unroll
  for (int r = 0; r < 4; r++) {
    float s = ss[r];
    s += __shfl_xor(s, 1, 64);
    s += __shfl_xor(s, 2, 64);
    s += __shfl_xor(s, 4, 64);
    s += __shfl_xor(s, 8, 64);
    ss[r] = 1.0f / fmaxf(sqrtf(s), 1e-12f);
  }
  __syncthreads();
#pragma unroll
  for (int nt = 0; nt < 8; nt++) {
#pragma unroll
    for (int r = 0; r < 4; r++) {
      unsigned short hv = f2bf(acc[nt][r] * ss[r]);
      *(unsigned short*)(As + (w * 16 + q * 4 + r) * 272 + (nt * 16 + m) * 2) = hv;
    }
  }
  __syncthreads();
  int rem = N_NODES - node0; if (rem > 64) rem = 64;
  for (int i = tid; i < 1024; i += 256) {
    int row = i >> 4, seg = i & 15;
    if (row < rem) {
      uint4 vv = *(const uint4*)(As + row * 272 + seg * 16);
      *(uint4*)((unsigned char*)outH + (size_t)(node0 + row) * 256 + seg * 16) = vv;
    }
  }
  if (FUSE_PROJ) {
    f32x4 accy = (f32x4){0.f, 0.f, 0.f, 0.f};
#pragma unroll
    for (int kc = 0; kc < 4; kc++) {
      bf16x8 af = *(const bf16x8*)(Abase + kc * 64);   // normalized H tile
      bf16x8 bfr = *(const bf16x8*)(pW2 + (size_t)(kc * 64 + l) * 16);
      accy = __builtin_amdgcn_mfma_f32_16x16x32_bf16(af, bfr, accy, 0, 0, 0);
    }
#pragma unroll
    for (int r = 0; r < 4; r++) {
      int orow = node0 + w * 16 + q * 4 + r;
      if (orow < N_NODES) y[(size_t)orow * ODIM + m] = accy[r];
    }
  }
}

// ===========================================================================
// Fused: aggy = gather16(y); logits = relu((1+eps)*y + aggy + b);
// probs = softmax. Wave per node (4/block); quarters split the edge list.
// ===========================================================================
__global__ __launch_bounds__(256) void gather16_final_kernel(
    const float* __restrict__ y, const int* __restrict__ row_ptr,
    const int2* __restrict__ ep, const float* __restrict__ b,
    const float* __restrict__ eps_p, float* __restrict__ out_logits,
    float* __restrict__ out_probs) {
  int lane = threadIdx.x & 63;
  int node = blockIdx.x * 4 + (threadIdx.x >> 6);
  if (node >= N_NODES) return;
  int f = lane & 15, eq = lane >> 4;
  int a = row_ptr[node], bnd = row_ptr[node + 1];
  float acc = 0.0f;
  int j = a + eq;
  for (; j + 8 <= bnd; j += 8) {
    int s0 = ep[j].x, s1 = ep[j + 4].x;
    acc += y[(size_t)s0 * ODIM + f] + y[(size_t)s1 * ODIM + f];
  }
  for (; j < bnd; j += 4) acc += y[(size_t)ep[j].x * ODIM + f];
  acc += __shfl_xor(acc, 16, 64);
  acc += __shfl_xor(acc, 32, 64);
  if (eq == 0) {
    float epf = 1.0f + *eps_p;
    size_t idx = (size_t)node * ODIM + f;
    float logit = fmaxf(fmaf(epf, y[idx], acc) + b[f], 0.0f);
    float mx = logit;
#pragma unroll
    for (int mm = 8; mm >= 1; mm >>= 1) mx = fmaxf(mx, __shfl_xor(mx, mm, 16));
    float e = __expf(logit - mx);
    float ssum = e;
#pragma unroll
    for (int mm = 8; mm >= 1; mm >>= 1) ssum += __shfl_xor(ssum, mm, 16);
    out_logits[idx] = logit;
    out_probs[idx] = e / ssum;
  }
}

// ===========================================================================
extern "C" void kernel_launch(void* const* d_in, const int* in_sizes, int n_in,
                              void* d_out, int out_size, void* d_ws, size_t ws_size,
                              hipStream_t stream) {
  const float* x = (const float*)d_in[0];
  const int* ei = (const int*)d_in[1];       // int64 in reference -> int32 on device
  const float* ew = (const float*)d_in[2];
  const float* W0 = (const float*)d_in[3];
  const float* b0 = (const float*)d_in[4];
  const float* e0 = (const float*)d_in[5];
  const float* W1 = (const float*)d_in[6];
  const float* b1 = (const float*)d_in[7];
  const float* e1 = (const float*)d_in[8];
  const float* W2 = (const float*)d_in[9];
  const float* b2 = (const float*)d_in[10];
  const float* e2 = (const float*)d_in[11];
  float* out = (float*)d_out;

  const int* srcp = ei;
  const int* dstp = ei + N_EDGES;

  // ---- workspace layout (~97 MB; 102.4 MB proven available) ----
  char* ws = (char*)d_ws;
  size_t off = 0;
  uint32* Agg = (uint32*)(ws + off);  off += (size_t)N_NODES * DIM * 2;   // 25.6 MB
  uint32* Xb  = (uint32*)(ws + off);  off += (size_t)N_NODES * DIM * 2;   // 25.6 MB
  uint32* H   = (uint32*)(ws + off);  off += (size_t)N_NODES * DIM * 2;   // 25.6 MB
  int2* epack = (int2*)(ws + off);    off += (size_t)N_EDGES * 8;         // 12.8 MB
  float* y    = (float*)(ws + off);   off += (size_t)N_NODES * ODIM * 4;  // 6.4 MB
  int* row_ptr = (int*)(ws + off);    off += (size_t)(N_NODES + 16) * 4;
  int* bcnt   = (int*)(ws + off);     off += 2048;
  int* bbase  = (int*)(ws + off);     off += 2048;
  int* bcur   = (int*)(ws + off);     off += 2048;
  unsigned short* pW0 = (unsigned short*)(ws + off); off += 32768;
  unsigned short* pW1 = (unsigned short*)(ws + off); off += 32768;
  unsigned short* pW2 = (unsigned short*)(ws + off); off += 4096;

  // ---- independent prep: cast x, pack weights ----
  cast_x_kernel<<<(N_NODES * (DIM / 2) + 255) / 256, 256, 0, stream>>>(
      (const float2*)x, Xb);
  packW128_kernel<<<64, 256, 0, stream>>>(W0, pW0);
  packW128_kernel<<<64, 256, 0, stream>>>(W1, pW1);
  packW16_kernel<<<8, 256, 0, stream>>>(W2, pW2);

  // ---- build CSR: bucket hist -> scan -> coarse partition -> fine sort ----
  hipMemsetAsync(bcnt, 0, NB * sizeof(int), stream);
  bucket_hist_kernel<<<PBLK, 256, 0, stream>>>(dstp, bcnt);
  bucket_scan_kernel<<<1, 512, 0, stream>>>(bcnt, bbase, bcur);
  coarse_partition_kernel<<<PBLK, 256, 0, stream>>>(srcp, dstp, ew, bcur, epack);
  fine_sort_kernel<<<NB, 256, 0, stream>>>(bbase, epack, row_ptr);

  int ggrid = (N_NODES + 3) / 4;       // 25000
  int mgrid = (N_NODES + 63) / 64;     // 1563

  // layer 0: agg0 = gather(Xb); H = mlp(Xb, agg0, W0)
  gather_bf16<<<ggrid, 256, 0, stream>>>(Xb, row_ptr, epack, Agg);
  gin_mlp_mfma<0><<<mgrid, 256, 0, stream>>>(Xb, Agg, (const unsigned char*)pW0,
                                             b0, e0, H, nullptr, nullptr);
  // layer 1 (+fused layer-2 projection): agg1 = gather(H); H,y = mlp(H, agg1)
  gather_bf16<<<ggrid, 256, 0, stream>>>(H, row_ptr, epack, Agg);
  gin_mlp_mfma<1><<<mgrid, 256, 0, stream>>>(H, Agg, (const unsigned char*)pW1,
                                             b1, e1, H,
                                             (const unsigned char*)pW2, y);
  // layer 2 tail: fused gather16 + bias/relu/softmax
  gather16_final_kernel<<<ggrid, 256, 0, stream>>>(y, row_ptr, epack, b2, e2,
                                                   out, out + (size_t)N_NODES * ODIM);
}